// Round 3
// baseline (1136.298 us; speedup 1.0000x reference)
//
#include <hip/hip_runtime.h>
#include <stdint.h>

#define BN_EPS 1e-5f

typedef __bf16 bf16x8 __attribute__((ext_vector_type(8)));
typedef float  f32x4  __attribute__((ext_vector_type(4)));
typedef unsigned short us4 __attribute__((ext_vector_type(4)));

__device__ __forceinline__ unsigned short f2bf(float f) {
    unsigned u = __float_as_uint(f);
    unsigned r = (u + 0x7FFFu + ((u >> 16) & 1u)) >> 16;
    return (unsigned short)r;
}
__device__ __forceinline__ unsigned pk2(float a, float b) {
    return (unsigned)f2bf(a) | ((unsigned)f2bf(b) << 16);
}
// packed bf16 pair subtract: (a - b) per 16-bit half, RNE
__device__ __forceinline__ unsigned bfsub2(unsigned a, unsigned b) {
    float al = __uint_as_float(a << 16), bl = __uint_as_float(b << 16);
    float ah = __uint_as_float(a & 0xFFFF0000u), bh = __uint_as_float(b & 0xFFFF0000u);
    return pk2(al - bl, ah - bh);
}
// order-preserving bf16 -> 16-bit key (monotone); 0 < every real key
__device__ __forceinline__ unsigned short bfkey(unsigned short h) {
    return (h & 0x8000u) ? (unsigned short)(~h) : (unsigned short)(h | 0x8000u);
}
__device__ __forceinline__ unsigned short unbfkey(unsigned short k) {
    return (k & 0x8000u) ? (unsigned short)(k & 0x7FFFu) : (unsigned short)(~k);
}
__device__ __forceinline__ unsigned unb2(unsigned k0, unsigned k1) {
    return (unsigned)unbfkey((unsigned short)k0)
         | ((unsigned)unbfkey((unsigned short)k1) << 16);
}
// LDS swizzle: row-major 256-col ushort tile, 16B blocks XOR'd by row&7.
// Bijective per row; keeps b128/b64 accesses intact; epilogue scalar writes
// land conflict-free (2 lanes/word), frag reads at the inherent b128 floor.
__device__ __forceinline__ int swz(int row, int k) {
    const int blk = k >> 3;
    const int sb = (blk & 24) | ((blk ^ row) & 7);
    return (row << 8) + (sb << 3) + (k & 7);
}

// prep: weight/const conversion + x->bf16 + target histogram (fused)
__global__ void prep_kernel(
    const float* __restrict__ x, const int* __restrict__ eidx,
    int E, int M, int NX,
    const float* __restrict__ W1, const float* __restrict__ W2, const float* __restrict__ W3,
    const float* __restrict__ b1, const float* __restrict__ g1, const float* __restrict__ be1,
    const float* __restrict__ m1, const float* __restrict__ v1,
    const float* __restrict__ b2, const float* __restrict__ g2, const float* __restrict__ be2,
    const float* __restrict__ m2, const float* __restrict__ v2,
    const float* __restrict__ b3, const float* __restrict__ g3, const float* __restrict__ be3,
    const float* __restrict__ m3, const float* __restrict__ v3,
    unsigned short* __restrict__ W1b, unsigned short* __restrict__ W2b,
    unsigned short* __restrict__ W3b, float* __restrict__ consts,
    unsigned short* __restrict__ xb, unsigned* __restrict__ count)
{
    const int idx = blockIdx.x * 256 + threadIdx.x;
    if (idx < 65536) {
        W1b[idx] = f2bf(W1[idx]);
        W2b[idx] = f2bf(W2[idx]);
        W3b[idx] = f2bf(W3[idx]);
    }
    if (idx < 768) {
        const int l = idx >> 8, c = idx & 255;
        const float* bp  = l == 0 ? b1  : (l == 1 ? b2  : b3);
        const float* gp  = l == 0 ? g1  : (l == 1 ? g2  : g3);
        const float* bep = l == 0 ? be1 : (l == 1 ? be2 : be3);
        const float* mp  = l == 0 ? m1  : (l == 1 ? m2  : m3);
        const float* vp  = l == 0 ? v1  : (l == 1 ? v2  : v3);
        const float s = gp[c] * rsqrtf(vp[c] + BN_EPS);
        consts[l * 768 + c]       = bp[c];
        consts[l * 768 + 256 + c] = s;
        consts[l * 768 + 512 + c] = bep[c] - mp[c] * s;
    }
    if (idx < NX) xb[idx] = f2bf(x[idx]);
    if (idx < M) {
        const int tgt = (idx < E) ? eidx[E + idx] : (idx - E);
        atomicAdd(&count[tgt], 1u);
    }
}

__global__ __launch_bounds__(1024) void scan_kernel(
    const unsigned* __restrict__ count, unsigned* __restrict__ cursor, int N)
{
    __shared__ unsigned part[1024];
    const int t = threadIdx.x;
    const int per = (N + 1023) / 1024;
    const int b = t * per;
    unsigned s = 0;
    for (int i = 0; i < per; i++) if (b + i < N) s += count[b + i];
    part[t] = s;
    __syncthreads();
    for (int off = 1; off < 1024; off <<= 1) {
        unsigned v = (t >= off) ? part[t - off] : 0u;
        __syncthreads();
        part[t] += v;
        __syncthreads();
    }
    unsigned run = (t > 0) ? part[t - 1] : 0u;
    for (int i = 0; i < per; i++) {
        if (b + i < N) {
            unsigned c = count[b + i];
            cursor[b + i] = run;
            run += c;
        }
    }
}

// scatter: emit (src,tgt) pairs in target-sorted position
__global__ void scatter_kernel(const int* __restrict__ eidx, int E, int M,
                               unsigned* __restrict__ cursor, int* __restrict__ spair)
{
    const int i = blockIdx.x * 256 + threadIdx.x;
    if (i < M) {
        int s, tg;
        if (i < E) { s = eidx[i]; tg = eidx[E + i]; }
        else       { s = tg = i - E; }
        const unsigned pos = atomicAdd(&cursor[tg], 1u);
        int2* p = (int2*)spair;
        p[pos] = make_int2(s, tg);
    }
}

// Fused: gather -> L1 -> L2 -> segmented max -> atomics
__global__ __launch_bounds__(256, 5) void msg_kernel(
    const unsigned short* __restrict__ xb,
    const int* __restrict__ spair,   // [M] (src,tgt) pairs, sorted by tgt
    int M,
    const unsigned short* __restrict__ W1b,
    const unsigned short* __restrict__ W2b,
    const float* __restrict__ consts,
    unsigned* __restrict__ agg)
{
    __shared__ unsigned short At[64 * 256];   // 32 KiB exactly -> 5 blocks/CU

    const int t = threadIdx.x;
    const int base = blockIdx.x * 64;

    // ---- gather: A = [x_i | x_j - x_i] in bf16 ----
    {
        const int row = t >> 2, part = t & 3;
        const int slot = base + row;
        const int c0 = part * 32;
        if (slot < M) {
            const int2 pr = *(const int2*)(spair + 2 * slot);   // (src, tgt)
            const unsigned short* xi = xb + (size_t)pr.y * 128;
            const unsigned short* xj = xb + (size_t)pr.x * 128;
            uint4 I[4], J[4];
            #pragma unroll
            for (int w = 0; w < 4; w++) I[w] = *(const uint4*)(xi + c0 + w * 8);
            #pragma unroll
            for (int w = 0; w < 4; w++) J[w] = *(const uint4*)(xj + c0 + w * 8);
            #pragma unroll
            for (int w = 0; w < 4; w++) {
                *(uint4*)&At[swz(row, c0 + w * 8)] = I[w];
                uint4 d;
                d.x = bfsub2(J[w].x, I[w].x);
                d.y = bfsub2(J[w].y, I[w].y);
                d.z = bfsub2(J[w].z, I[w].z);
                d.w = bfsub2(J[w].w, I[w].w);
                *(uint4*)&At[swz(row, 128 + c0 + w * 8)] = d;
            }
        } else {
            const uint4 z = {0u, 0u, 0u, 0u};
            #pragma unroll
            for (int w = 0; w < 4; w++) {
                *(uint4*)&At[swz(row, c0 + w * 8)] = z;
                *(uint4*)&At[swz(row, 128 + c0 + w * 8)] = z;
            }
        }
    }
    __syncthreads();

    const int lane = t & 63;
    const int wv   = t >> 6;
    const int n16  = lane & 15;
    const int qd   = lane >> 4;
    const int wc   = wv * 64;

    const f32x4 vzero = {0.f, 0.f, 0.f, 0.f};
    f32x4 acc[4][4];
    #pragma unroll
    for (int i = 0; i < 4; i++)
        #pragma unroll
        for (int j = 0; j < 4; j++) acc[i][j] = vzero;

    // ---- GEMM1 ----
    #pragma unroll
    for (int ks = 0; ks < 8; ks++) {
        const int k0 = ks * 32 + qd * 8;
        bf16x8 a[4];
        #pragma unroll
        for (int ri = 0; ri < 4; ri++)
            a[ri] = *(const bf16x8*)&At[swz(ri * 16 + n16, k0)];
        #pragma unroll
        for (int ci = 0; ci < 4; ci++) {
            bf16x8 b = *(const bf16x8*)&W1b[(size_t)(wc + ci * 16 + n16) * 256 + k0];
            #pragma unroll
            for (int ri = 0; ri < 4; ri++)
                acc[ri][ci] = __builtin_amdgcn_mfma_f32_16x16x32_bf16(a[ri], b, acc[ri][ci], 0, 0, 0);
        }
    }
    __syncthreads();

    // ---- epilogue1 -> bf16 h1 back into At ----
    {
        const float* B1 = consts;
        const float* S1 = consts + 256;
        const float* T1 = consts + 512;
        #pragma unroll
        for (int ci = 0; ci < 4; ci++) {
            const int col = wc + ci * 16 + n16;
            const float bb = B1[col], ss = S1[col], tt = T1[col];
            #pragma unroll
            for (int ri = 0; ri < 4; ri++) {
                #pragma unroll
                for (int r = 0; r < 4; r++) {
                    const int row = ri * 16 + qd * 4 + r;
                    float v = fmaxf(acc[ri][ci][r] + bb, 0.f) * ss + tt;
                    At[swz(row, col)] = f2bf(v);
                }
                acc[ri][ci] = vzero;
            }
        }
    }
    __syncthreads();

    // ---- GEMM2 ----
    #pragma unroll
    for (int ks = 0; ks < 8; ks++) {
        const int k0 = ks * 32 + qd * 8;
        bf16x8 a[4];
        #pragma unroll
        for (int ri = 0; ri < 4; ri++)
            a[ri] = *(const bf16x8*)&At[swz(ri * 16 + n16, k0)];
        #pragma unroll
        for (int ci = 0; ci < 4; ci++) {
            bf16x8 b = *(const bf16x8*)&W2b[(size_t)(wc + ci * 16 + n16) * 256 + k0];
            #pragma unroll
            for (int ri = 0; ri < 4; ri++)
                acc[ri][ci] = __builtin_amdgcn_mfma_f32_16x16x32_bf16(a[ri], b, acc[ri][ci], 0, 0, 0);
        }
    }
    __syncthreads();

    // ---- epilogue2 -> 16-bit keys into At ----
    {
        const float* B2 = consts + 768;
        const float* S2 = consts + 768 + 256;
        const float* T2 = consts + 768 + 512;
        #pragma unroll
        for (int ci = 0; ci < 4; ci++) {
            const int col = wc + ci * 16 + n16;
            const float bb = B2[col], ss = S2[col], tt = T2[col];
            #pragma unroll
            for (int ri = 0; ri < 4; ri++) {
                #pragma unroll
                for (int r = 0; r < 4; r++) {
                    const int row = ri * 16 + qd * 4 + r;
                    float v = fmaxf(acc[ri][ci][r] + bb, 0.f) * ss + tt;
                    At[swz(row, col)] = bfkey(f2bf(v));
                }
            }
        }
    }
    __syncthreads();

    // ---- segmented max: wave = 16 rows, lane = 4 cols, b64 reads ----
    {
        const int c4 = lane * 4;
        const int slot = base + wv * 16 + lane;
        const int myt = (lane < 16 && slot < M) ? spair[2 * slot + 1] : -1;
        int curT = -1;
        unsigned m0 = 0, m1 = 0, m2 = 0, m3 = 0;
        for (int r = 0; r < 16; r++) {
            const int tg = __shfl(myt, r);            // wave-uniform
            us4 k = *(const us4*)&At[swz(wv * 16 + r, c4)];
            if (tg != curT) {
                if (curT >= 0) {
                    unsigned* p = &agg[(size_t)curT * 256 + c4];
                    atomicMax(p, m0); atomicMax(p + 1, m1);
                    atomicMax(p + 2, m2); atomicMax(p + 3, m3);
                }
                curT = tg;
                m0 = k.x; m1 = k.y; m2 = k.z; m3 = k.w;
            } else {
                m0 = m0 > (unsigned)k.x ? m0 : (unsigned)k.x;
                m1 = m1 > (unsigned)k.y ? m1 : (unsigned)k.y;
                m2 = m2 > (unsigned)k.z ? m2 : (unsigned)k.z;
                m3 = m3 > (unsigned)k.w ? m3 : (unsigned)k.w;
            }
        }
        if (curT >= 0) {
            unsigned* p = &agg[(size_t)curT * 256 + c4];
            atomicMax(p, m0); atomicMax(p + 1, m1);
            atomicMax(p + 2, m2); atomicMax(p + 3, m3);
        }
    }
}

// Final layer: 32-row tiles for better CU balance (625 blocks)
__global__ __launch_bounds__(256) void out_kernel(
    const unsigned* __restrict__ agg, int N,
    const unsigned short* __restrict__ W3b,
    const float* __restrict__ consts,
    float* __restrict__ out)
{
    __shared__ unsigned short At[32 * 256];

    const int t = threadIdx.x;
    const int base = blockIdx.x * 32;

    {
        const int row = t >> 3, part = t & 7;
        const int node = base + row;
        const int c0 = part * 32;
        if (node < N) {
            const unsigned* ap = agg + (size_t)node * 256 + c0;
            #pragma unroll
            for (int w = 0; w < 4; w++) {
                uint4 a = *(const uint4*)(ap + w * 8);
                uint4 b = *(const uint4*)(ap + w * 8 + 4);
                uint4 p;
                p.x = unb2(a.x, a.y); p.y = unb2(a.z, a.w);
                p.z = unb2(b.x, b.y); p.w = unb2(b.z, b.w);
                *(uint4*)&At[swz(row, c0 + w * 8)] = p;
            }
        } else {
            const uint4 z = {0u, 0u, 0u, 0u};
            #pragma unroll
            for (int w = 0; w < 4; w++) *(uint4*)&At[swz(row, c0 + w * 8)] = z;
        }
    }
    __syncthreads();

    const int lane = t & 63;
    const int wv   = t >> 6;
    const int n16  = lane & 15;
    const int qd   = lane >> 4;
    const int wc   = wv * 64;

    const f32x4 vzero = {0.f, 0.f, 0.f, 0.f};
    f32x4 acc[2][4];
    #pragma unroll
    for (int i = 0; i < 2; i++)
        #pragma unroll
        for (int j = 0; j < 4; j++) acc[i][j] = vzero;

    #pragma unroll
    for (int ks = 0; ks < 8; ks++) {
        const int k0 = ks * 32 + qd * 8;
        bf16x8 a[2];
        #pragma unroll
        for (int ri = 0; ri < 2; ri++)
            a[ri] = *(const bf16x8*)&At[swz(ri * 16 + n16, k0)];
        #pragma unroll
        for (int ci = 0; ci < 4; ci++) {
            bf16x8 b = *(const bf16x8*)&W3b[(size_t)(wc + ci * 16 + n16) * 256 + k0];
            #pragma unroll
            for (int ri = 0; ri < 2; ri++)
                acc[ri][ci] = __builtin_amdgcn_mfma_f32_16x16x32_bf16(a[ri], b, acc[ri][ci], 0, 0, 0);
        }
    }

    {
        const float* B3 = consts + 1536;
        const float* S3 = consts + 1536 + 256;
        const float* T3 = consts + 1536 + 512;
        #pragma unroll
        for (int ci = 0; ci < 4; ci++) {
            const int col = wc + ci * 16 + n16;
            const float bb = B3[col], ss = S3[col], tt = T3[col];
            #pragma unroll
            for (int ri = 0; ri < 2; ri++) {
                #pragma unroll
                for (int r = 0; r < 4; r++) {
                    const int row = ri * 16 + qd * 4 + r;
                    const int node = base + row;
                    if (node < N) {
                        float v = fmaxf(acc[ri][ci][r] + bb, 0.f) * ss + tt;
                        out[(size_t)node * 256 + col] = v;
                    }
                }
            }
        }
    }
}

extern "C" void kernel_launch(void* const* d_in, const int* in_sizes, int n_in,
                              void* d_out, int out_size, void* d_ws, size_t ws_size,
                              hipStream_t stream)
{
    const float* x  = (const float*)d_in[0];
    const int* eidx = (const int*)d_in[1];
    const int N = in_sizes[0] / 128;
    const int NX = in_sizes[0];
    const int E = in_sizes[1] / 2;
    const int M = E + N;

    char* ws = (char*)d_ws;
    unsigned short* W1b = (unsigned short*)(ws);
    unsigned short* W2b = (unsigned short*)(ws + 131072);
    unsigned short* W3b = (unsigned short*)(ws + 262144);
    float* consts       = (float*)(ws + 393216);                 // 2304 f32
    size_t off = 402432;
    unsigned short* xb  = (unsigned short*)(ws + off); off += (size_t)NX * 2;
    unsigned* agg       = (unsigned*)(ws + off);       off += (size_t)N * 256 * 4;
    unsigned* count     = (unsigned*)(ws + off);       off += (size_t)N * 4;
    unsigned* cursor    = (unsigned*)(ws + off);       off += (size_t)N * 4;
    int* spair          = (int*)(ws + off);            // M int2

    hipMemsetAsync(agg, 0, (size_t)N * 256 * 4, stream);
    hipMemsetAsync(count, 0, (size_t)N * 4, stream);

    int work = NX;
    if (M > work) work = M;
    if (65536 > work) work = 65536;
    hipLaunchKernelGGL(prep_kernel, dim3((work + 255) / 256), dim3(256), 0, stream,
        x, eidx, E, M, NX,
        (const float*)d_in[2], (const float*)d_in[8], (const float*)d_in[14],
        (const float*)d_in[3], (const float*)d_in[4], (const float*)d_in[5],
        (const float*)d_in[6], (const float*)d_in[7],
        (const float*)d_in[9], (const float*)d_in[10], (const float*)d_in[11],
        (const float*)d_in[12], (const float*)d_in[13],
        (const float*)d_in[15], (const float*)d_in[16], (const float*)d_in[17],
        (const float*)d_in[18], (const float*)d_in[19],
        W1b, W2b, W3b, consts, xb, count);

    hipLaunchKernelGGL(scan_kernel, dim3(1), dim3(1024), 0, stream,
        count, cursor, N);
    hipLaunchKernelGGL(scatter_kernel, dim3((M + 255) / 256), dim3(256), 0, stream,
        eidx, E, M, cursor, spair);

    hipLaunchKernelGGL(msg_kernel, dim3((M + 63) / 64), dim3(256), 0, stream,
        xb, spair, M, W1b, W2b, consts, agg);

    hipLaunchKernelGGL(out_kernel, dim3((N + 31) / 32), dim3(256), 0, stream,
        agg, N, W3b, consts, (float*)d_out);
}

// Round 4
// 673.997 us; speedup vs baseline: 1.6859x; 1.6859x over previous
//
#include <hip/hip_runtime.h>
#include <stdint.h>

#define BN_EPS 1e-5f

typedef __bf16 bf16x8 __attribute__((ext_vector_type(8)));
typedef float  f32x4  __attribute__((ext_vector_type(4)));
typedef unsigned short us4 __attribute__((ext_vector_type(4)));

__device__ __forceinline__ unsigned short f2bf(float f) {
    unsigned u = __float_as_uint(f);
    unsigned r = (u + 0x7FFFu + ((u >> 16) & 1u)) >> 16;
    return (unsigned short)r;
}
__device__ __forceinline__ unsigned pk2(float a, float b) {
    return (unsigned)f2bf(a) | ((unsigned)f2bf(b) << 16);
}
// packed bf16 pair subtract: (a - b) per 16-bit half, RNE
__device__ __forceinline__ unsigned bfsub2(unsigned a, unsigned b) {
    float al = __uint_as_float(a << 16), bl = __uint_as_float(b << 16);
    float ah = __uint_as_float(a & 0xFFFF0000u), bh = __uint_as_float(b & 0xFFFF0000u);
    return pk2(al - bl, ah - bh);
}
// order-preserving bf16 -> 16-bit key (monotone); 0 < every real key
__device__ __forceinline__ unsigned short bfkey(unsigned short h) {
    return (h & 0x8000u) ? (unsigned short)(~h) : (unsigned short)(h | 0x8000u);
}
__device__ __forceinline__ unsigned short unbfkey(unsigned short k) {
    return (k & 0x8000u) ? (unsigned short)(k & 0x7FFFu) : (unsigned short)(~k);
}
__device__ __forceinline__ unsigned unb2(unsigned k0, unsigned k1) {
    return (unsigned)unbfkey((unsigned short)k0)
         | ((unsigned)unbfkey((unsigned short)k1) << 16);
}
// LDS swizzle: row-major 256-col ushort tile, 16B blocks XOR'd by row&7.
__device__ __forceinline__ int swz(int row, int k) {
    const int blk = k >> 3;
    const int sb = (blk & 24) | ((blk ^ row) & 7);
    return (row << 8) + (sb << 3) + (k & 7);
}

// prep: weight/const conversion + x->bf16 + target histogram (fused)
__global__ void prep_kernel(
    const float* __restrict__ x, const int* __restrict__ eidx,
    int E, int M, int NX,
    const float* __restrict__ W1, const float* __restrict__ W2, const float* __restrict__ W3,
    const float* __restrict__ b1, const float* __restrict__ g1, const float* __restrict__ be1,
    const float* __restrict__ m1, const float* __restrict__ v1,
    const float* __restrict__ b2, const float* __restrict__ g2, const float* __restrict__ be2,
    const float* __restrict__ m2, const float* __restrict__ v2,
    const float* __restrict__ b3, const float* __restrict__ g3, const float* __restrict__ be3,
    const float* __restrict__ m3, const float* __restrict__ v3,
    unsigned short* __restrict__ W1b, unsigned short* __restrict__ W2b,
    unsigned short* __restrict__ W3b, float* __restrict__ consts,
    unsigned short* __restrict__ xb, unsigned* __restrict__ count)
{
    const int idx = blockIdx.x * 256 + threadIdx.x;
    if (idx < 65536) {
        W1b[idx] = f2bf(W1[idx]);
        W2b[idx] = f2bf(W2[idx]);
        W3b[idx] = f2bf(W3[idx]);
    }
    if (idx < 768) {
        const int l = idx >> 8, c = idx & 255;
        const float* bp  = l == 0 ? b1  : (l == 1 ? b2  : b3);
        const float* gp  = l == 0 ? g1  : (l == 1 ? g2  : g3);
        const float* bep = l == 0 ? be1 : (l == 1 ? be2 : be3);
        const float* mp  = l == 0 ? m1  : (l == 1 ? m2  : m3);
        const float* vp  = l == 0 ? v1  : (l == 1 ? v2  : v3);
        const float s = gp[c] * rsqrtf(vp[c] + BN_EPS);
        consts[l * 768 + c]       = bp[c];
        consts[l * 768 + 256 + c] = s;
        consts[l * 768 + 512 + c] = bep[c] - mp[c] * s;
    }
    if (idx < NX) xb[idx] = f2bf(x[idx]);
    if (idx < M) {
        const int tgt = (idx < E) ? eidx[E + idx] : (idx - E);
        atomicAdd(&count[tgt], 1u);
    }
}

__global__ __launch_bounds__(1024) void scan_kernel(
    const unsigned* __restrict__ count, unsigned* __restrict__ cursor, int N)
{
    __shared__ unsigned part[1024];
    const int t = threadIdx.x;
    const int per = (N + 1023) / 1024;
    const int b = t * per;
    unsigned s = 0;
    for (int i = 0; i < per; i++) if (b + i < N) s += count[b + i];
    part[t] = s;
    __syncthreads();
    for (int off = 1; off < 1024; off <<= 1) {
        unsigned v = (t >= off) ? part[t - off] : 0u;
        __syncthreads();
        part[t] += v;
        __syncthreads();
    }
    unsigned run = (t > 0) ? part[t - 1] : 0u;
    for (int i = 0; i < per; i++) {
        if (b + i < N) {
            unsigned c = count[b + i];
            cursor[b + i] = run;
            run += c;
        }
    }
}

// scatter: emit (src,tgt) pairs in target-sorted position
__global__ void scatter_kernel(const int* __restrict__ eidx, int E, int M,
                               unsigned* __restrict__ cursor, int* __restrict__ spair)
{
    const int i = blockIdx.x * 256 + threadIdx.x;
    if (i < M) {
        int s, tg;
        if (i < E) { s = eidx[i]; tg = eidx[E + i]; }
        else       { s = tg = i - E; }
        const unsigned pos = atomicAdd(&cursor[tg], 1u);
        int2* p = (int2*)spair;
        p[pos] = make_int2(s, tg);
    }
}

// Fused: gather -> L1 -> L2 -> segmented max -> atomics
// NOTE: plain __launch_bounds__(256). (256,5) forced acc[4][4] to spill to
// scratch (VGPR 84->48, WRITE_SIZE 30MB->2.7GB, +420us). Registers win.
__global__ __launch_bounds__(256) void msg_kernel(
    const unsigned short* __restrict__ xb,
    const int* __restrict__ spair,   // [M] (src,tgt) pairs, sorted by tgt
    int M,
    const unsigned short* __restrict__ W1b,
    const unsigned short* __restrict__ W2b,
    const float* __restrict__ consts,
    unsigned* __restrict__ agg)
{
    __shared__ unsigned short At[64 * 256];   // 32 KiB

    const int t = threadIdx.x;
    const int base = blockIdx.x * 64;

    // ---- gather: A = [x_i | x_j - x_i] in bf16 ----
    {
        const int row = t >> 2, part = t & 3;
        const int slot = base + row;
        const int c0 = part * 32;
        if (slot < M) {
            const int2 pr = *(const int2*)(spair + 2 * slot);   // (src, tgt)
            const unsigned short* xi = xb + (size_t)pr.y * 128;
            const unsigned short* xj = xb + (size_t)pr.x * 128;
            uint4 I[4], J[4];
            #pragma unroll
            for (int w = 0; w < 4; w++) I[w] = *(const uint4*)(xi + c0 + w * 8);
            #pragma unroll
            for (int w = 0; w < 4; w++) J[w] = *(const uint4*)(xj + c0 + w * 8);
            #pragma unroll
            for (int w = 0; w < 4; w++) {
                *(uint4*)&At[swz(row, c0 + w * 8)] = I[w];
                uint4 d;
                d.x = bfsub2(J[w].x, I[w].x);
                d.y = bfsub2(J[w].y, I[w].y);
                d.z = bfsub2(J[w].z, I[w].z);
                d.w = bfsub2(J[w].w, I[w].w);
                *(uint4*)&At[swz(row, 128 + c0 + w * 8)] = d;
            }
        } else {
            const uint4 z = {0u, 0u, 0u, 0u};
            #pragma unroll
            for (int w = 0; w < 4; w++) {
                *(uint4*)&At[swz(row, c0 + w * 8)] = z;
                *(uint4*)&At[swz(row, 128 + c0 + w * 8)] = z;
            }
        }
    }
    __syncthreads();

    const int lane = t & 63;
    const int wv   = t >> 6;
    const int n16  = lane & 15;
    const int qd   = lane >> 4;
    const int wc   = wv * 64;

    const f32x4 vzero = {0.f, 0.f, 0.f, 0.f};
    f32x4 acc[4][4];
    #pragma unroll
    for (int i = 0; i < 4; i++)
        #pragma unroll
        for (int j = 0; j < 4; j++) acc[i][j] = vzero;

    // ---- GEMM1 ----
    #pragma unroll
    for (int ks = 0; ks < 8; ks++) {
        const int k0 = ks * 32 + qd * 8;
        bf16x8 a[4];
        #pragma unroll
        for (int ri = 0; ri < 4; ri++)
            a[ri] = *(const bf16x8*)&At[swz(ri * 16 + n16, k0)];
        #pragma unroll
        for (int ci = 0; ci < 4; ci++) {
            bf16x8 b = *(const bf16x8*)&W1b[(size_t)(wc + ci * 16 + n16) * 256 + k0];
            #pragma unroll
            for (int ri = 0; ri < 4; ri++)
                acc[ri][ci] = __builtin_amdgcn_mfma_f32_16x16x32_bf16(a[ri], b, acc[ri][ci], 0, 0, 0);
        }
    }
    __syncthreads();

    // ---- epilogue1 -> bf16 h1 back into At ----
    {
        const float* B1 = consts;
        const float* S1 = consts + 256;
        const float* T1 = consts + 512;
        #pragma unroll
        for (int ci = 0; ci < 4; ci++) {
            const int col = wc + ci * 16 + n16;
            const float bb = B1[col], ss = S1[col], tt = T1[col];
            #pragma unroll
            for (int ri = 0; ri < 4; ri++) {
                #pragma unroll
                for (int r = 0; r < 4; r++) {
                    const int row = ri * 16 + qd * 4 + r;
                    float v = fmaxf(acc[ri][ci][r] + bb, 0.f) * ss + tt;
                    At[swz(row, col)] = f2bf(v);
                }
                acc[ri][ci] = vzero;
            }
        }
    }
    __syncthreads();

    // ---- GEMM2 ----
    #pragma unroll
    for (int ks = 0; ks < 8; ks++) {
        const int k0 = ks * 32 + qd * 8;
        bf16x8 a[4];
        #pragma unroll
        for (int ri = 0; ri < 4; ri++)
            a[ri] = *(const bf16x8*)&At[swz(ri * 16 + n16, k0)];
        #pragma unroll
        for (int ci = 0; ci < 4; ci++) {
            bf16x8 b = *(const bf16x8*)&W2b[(size_t)(wc + ci * 16 + n16) * 256 + k0];
            #pragma unroll
            for (int ri = 0; ri < 4; ri++)
                acc[ri][ci] = __builtin_amdgcn_mfma_f32_16x16x32_bf16(a[ri], b, acc[ri][ci], 0, 0, 0);
        }
    }
    __syncthreads();

    // ---- epilogue2 -> 16-bit keys into At ----
    {
        const float* B2 = consts + 768;
        const float* S2 = consts + 768 + 256;
        const float* T2 = consts + 768 + 512;
        #pragma unroll
        for (int ci = 0; ci < 4; ci++) {
            const int col = wc + ci * 16 + n16;
            const float bb = B2[col], ss = S2[col], tt = T2[col];
            #pragma unroll
            for (int ri = 0; ri < 4; ri++) {
                #pragma unroll
                for (int r = 0; r < 4; r++) {
                    const int row = ri * 16 + qd * 4 + r;
                    float v = fmaxf(acc[ri][ci][r] + bb, 0.f) * ss + tt;
                    At[swz(row, col)] = bfkey(f2bf(v));
                }
            }
        }
    }
    __syncthreads();

    // ---- segmented max: wave = 16 rows, lane = 4 cols, b64 reads ----
    {
        const int c4 = lane * 4;
        const int slot = base + wv * 16 + lane;
        const int myt = (lane < 16 && slot < M) ? spair[2 * slot + 1] : -1;
        int curT = -1;
        unsigned m0 = 0, m1 = 0, m2 = 0, m3 = 0;
        for (int r = 0; r < 16; r++) {
            const int tg = __shfl(myt, r);            // wave-uniform
            us4 k = *(const us4*)&At[swz(wv * 16 + r, c4)];
            if (tg != curT) {
                if (curT >= 0) {
                    unsigned* p = &agg[(size_t)curT * 256 + c4];
                    atomicMax(p, m0); atomicMax(p + 1, m1);
                    atomicMax(p + 2, m2); atomicMax(p + 3, m3);
                }
                curT = tg;
                m0 = k.x; m1 = k.y; m2 = k.z; m3 = k.w;
            } else {
                m0 = m0 > (unsigned)k.x ? m0 : (unsigned)k.x;
                m1 = m1 > (unsigned)k.y ? m1 : (unsigned)k.y;
                m2 = m2 > (unsigned)k.z ? m2 : (unsigned)k.z;
                m3 = m3 > (unsigned)k.w ? m3 : (unsigned)k.w;
            }
        }
        if (curT >= 0) {
            unsigned* p = &agg[(size_t)curT * 256 + c4];
            atomicMax(p, m0); atomicMax(p + 1, m1);
            atomicMax(p + 2, m2); atomicMax(p + 3, m3);
        }
    }
}

// Final layer: 32-row tiles for better CU balance (625 blocks)
__global__ __launch_bounds__(256) void out_kernel(
    const unsigned* __restrict__ agg, int N,
    const unsigned short* __restrict__ W3b,
    const float* __restrict__ consts,
    float* __restrict__ out)
{
    __shared__ unsigned short At[32 * 256];

    const int t = threadIdx.x;
    const int base = blockIdx.x * 32;

    {
        const int row = t >> 3, part = t & 7;
        const int node = base + row;
        const int c0 = part * 32;
        if (node < N) {
            const unsigned* ap = agg + (size_t)node * 256 + c0;
            #pragma unroll
            for (int w = 0; w < 4; w++) {
                uint4 a = *(const uint4*)(ap + w * 8);
                uint4 b = *(const uint4*)(ap + w * 8 + 4);
                uint4 p;
                p.x = unb2(a.x, a.y); p.y = unb2(a.z, a.w);
                p.z = unb2(b.x, b.y); p.w = unb2(b.z, b.w);
                *(uint4*)&At[swz(row, c0 + w * 8)] = p;
            }
        } else {
            const uint4 z = {0u, 0u, 0u, 0u};
            #pragma unroll
            for (int w = 0; w < 4; w++) *(uint4*)&At[swz(row, c0 + w * 8)] = z;
        }
    }
    __syncthreads();

    const int lane = t & 63;
    const int wv   = t >> 6;
    const int n16  = lane & 15;
    const int qd   = lane >> 4;
    const int wc   = wv * 64;

    const f32x4 vzero = {0.f, 0.f, 0.f, 0.f};
    f32x4 acc[2][4];
    #pragma unroll
    for (int i = 0; i < 2; i++)
        #pragma unroll
        for (int j = 0; j < 4; j++) acc[i][j] = vzero;

    #pragma unroll
    for (int ks = 0; ks < 8; ks++) {
        const int k0 = ks * 32 + qd * 8;
        bf16x8 a[2];
        #pragma unroll
        for (int ri = 0; ri < 2; ri++)
            a[ri] = *(const bf16x8*)&At[swz(ri * 16 + n16, k0)];
        #pragma unroll
        for (int ci = 0; ci < 4; ci++) {
            bf16x8 b = *(const bf16x8*)&W3b[(size_t)(wc + ci * 16 + n16) * 256 + k0];
            #pragma unroll
            for (int ri = 0; ri < 2; ri++)
                acc[ri][ci] = __builtin_amdgcn_mfma_f32_16x16x32_bf16(a[ri], b, acc[ri][ci], 0, 0, 0);
        }
    }

    {
        const float* B3 = consts + 1536;
        const float* S3 = consts + 1536 + 256;
        const float* T3 = consts + 1536 + 512;
        #pragma unroll
        for (int ci = 0; ci < 4; ci++) {
            const int col = wc + ci * 16 + n16;
            const float bb = B3[col], ss = S3[col], tt = T3[col];
            #pragma unroll
            for (int ri = 0; ri < 2; ri++) {
                #pragma unroll
                for (int r = 0; r < 4; r++) {
                    const int row = ri * 16 + qd * 4 + r;
                    const int node = base + row;
                    if (node < N) {
                        float v = fmaxf(acc[ri][ci][r] + bb, 0.f) * ss + tt;
                        out[(size_t)node * 256 + col] = v;
                    }
                }
            }
        }
    }
}

extern "C" void kernel_launch(void* const* d_in, const int* in_sizes, int n_in,
                              void* d_out, int out_size, void* d_ws, size_t ws_size,
                              hipStream_t stream)
{
    const float* x  = (const float*)d_in[0];
    const int* eidx = (const int*)d_in[1];
    const int N = in_sizes[0] / 128;
    const int NX = in_sizes[0];
    const int E = in_sizes[1] / 2;
    const int M = E + N;

    char* ws = (char*)d_ws;
    unsigned short* W1b = (unsigned short*)(ws);
    unsigned short* W2b = (unsigned short*)(ws + 131072);
    unsigned short* W3b = (unsigned short*)(ws + 262144);
    float* consts       = (float*)(ws + 393216);                 // 2304 f32
    size_t off = 402432;
    unsigned short* xb  = (unsigned short*)(ws + off); off += (size_t)NX * 2;
    unsigned* agg       = (unsigned*)(ws + off);       off += (size_t)N * 256 * 4;
    unsigned* count     = (unsigned*)(ws + off);       off += (size_t)N * 4;
    unsigned* cursor    = (unsigned*)(ws + off);       off += (size_t)N * 4;
    int* spair          = (int*)(ws + off);            // M int2

    hipMemsetAsync(agg, 0, (size_t)N * 256 * 4, stream);
    hipMemsetAsync(count, 0, (size_t)N * 4, stream);

    int work = NX;
    if (M > work) work = M;
    if (65536 > work) work = 65536;
    hipLaunchKernelGGL(prep_kernel, dim3((work + 255) / 256), dim3(256), 0, stream,
        x, eidx, E, M, NX,
        (const float*)d_in[2], (const float*)d_in[8], (const float*)d_in[14],
        (const float*)d_in[3], (const float*)d_in[4], (const float*)d_in[5],
        (const float*)d_in[6], (const float*)d_in[7],
        (const float*)d_in[9], (const float*)d_in[10], (const float*)d_in[11],
        (const float*)d_in[12], (const float*)d_in[13],
        (const float*)d_in[15], (const float*)d_in[16], (const float*)d_in[17],
        (const float*)d_in[18], (const float*)d_in[19],
        W1b, W2b, W3b, consts, xb, count);

    hipLaunchKernelGGL(scan_kernel, dim3(1), dim3(1024), 0, stream,
        count, cursor, N);
    hipLaunchKernelGGL(scatter_kernel, dim3((M + 255) / 256), dim3(256), 0, stream,
        eidx, E, M, cursor, spair);

    hipLaunchKernelGGL(msg_kernel, dim3((M + 63) / 64), dim3(256), 0, stream,
        xb, spair, M, W1b, W2b, consts, agg);

    hipLaunchKernelGGL(out_kernel, dim3((N + 31) / 32), dim3(256), 0, stream,
        agg, N, W3b, consts, (float*)d_out);
}

// Round 5
// 640.759 us; speedup vs baseline: 1.7734x; 1.0519x over previous
//
#include <hip/hip_runtime.h>
#include <stdint.h>

#define BN_EPS 1e-5f

typedef __bf16 bf16x8 __attribute__((ext_vector_type(8)));
typedef float  f32x4  __attribute__((ext_vector_type(4)));

__device__ __forceinline__ unsigned short f2bf(float f) {
    unsigned u = __float_as_uint(f);
    unsigned r = (u + 0x7FFFu + ((u >> 16) & 1u)) >> 16;
    return (unsigned short)r;
}
__device__ __forceinline__ unsigned pk2(float a, float b) {
    return (unsigned)f2bf(a) | ((unsigned)f2bf(b) << 16);
}
// order-preserving bf16 -> 16-bit key (monotone); 0 < every real key
__device__ __forceinline__ unsigned short bfkey(unsigned short h) {
    return (h & 0x8000u) ? (unsigned short)(~h) : (unsigned short)(h | 0x8000u);
}
__device__ __forceinline__ unsigned short unbfkey(unsigned short k) {
    return (k & 0x8000u) ? (unsigned short)(k & 0x7FFFu) : (unsigned short)(~k);
}
__device__ __forceinline__ unsigned unb2(unsigned k0, unsigned k1) {
    return (unsigned)unbfkey((unsigned short)k0)
         | ((unsigned)unbfkey((unsigned short)k1) << 16);
}
__device__ __forceinline__ unsigned kk2(float a, float b) {
    return (unsigned)bfkey(f2bf(a)) | ((unsigned)bfkey(f2bf(b)) << 16);
}
// LDS swizzle: row-major 256-col ushort tile, 16B blocks XOR'd by row&7.
__device__ __forceinline__ int swz(int row, int k) {
    const int blk = k >> 3;
    const int sb = (blk & 24) | ((blk ^ row) & 7);
    return (row << 8) + (sb << 3) + (k & 7);
}

// prep: W1' fold (edge-diff into weights), W2' fold (BN1 scale), b2'' matvec,
// W3 convert, BN consts, x->bf16, target histogram
__global__ void prep_kernel(
    const float* __restrict__ x, const int* __restrict__ eidx,
    int E, int M, int NX,
    const float* __restrict__ W1, const float* __restrict__ W2, const float* __restrict__ W3,
    const float* __restrict__ b1, const float* __restrict__ g1, const float* __restrict__ be1,
    const float* __restrict__ m1, const float* __restrict__ v1,
    const float* __restrict__ b2, const float* __restrict__ g2, const float* __restrict__ be2,
    const float* __restrict__ m2, const float* __restrict__ v2,
    const float* __restrict__ b3, const float* __restrict__ g3, const float* __restrict__ be3,
    const float* __restrict__ m3, const float* __restrict__ v3,
    unsigned short* __restrict__ W1b, unsigned short* __restrict__ W2b,
    unsigned short* __restrict__ W3b, float* __restrict__ consts,
    unsigned short* __restrict__ xb, unsigned* __restrict__ count)
{
    const int idx = blockIdx.x * 256 + threadIdx.x;
    if (idx < 65536) {
        const int row = idx >> 8, c = idx & 255;
        // W1' = [W1a - W1b | W1b]  (fold (xj-xi) into weights; A-tile = [xi|xj])
        float w1v = (c < 128) ? (W1[row * 256 + c] - W1[row * 256 + c + 128])
                              : W1[row * 256 + c];
        W1b[idx] = f2bf(w1v);
        // W2' = W2 * s1  (fold BN1 scale into W2's input channels)
        const float s1c = g1[c] * rsqrtf(v1[c] + BN_EPS);
        W2b[idx] = f2bf(W2[idx] * s1c);
        W3b[idx] = f2bf(W3[idx]);
    }
    if (idx < 768) {
        const int l = idx >> 8, c = idx & 255;
        const float* bp  = l == 0 ? b1  : (l == 1 ? b2  : b3);
        const float* gp  = l == 0 ? g1  : (l == 1 ? g2  : g3);
        const float* bep = l == 0 ? be1 : (l == 1 ? be2 : be3);
        const float* mp  = l == 0 ? m1  : (l == 1 ? m2  : m3);
        const float* vp  = l == 0 ? v1  : (l == 1 ? v2  : v3);
        const float s = gp[c] * rsqrtf(vp[c] + BN_EPS);
        float bias = bp[c];
        if (l == 1) {
            // b2'' = b2 + W2 @ t1  (fold BN1 shift); t1 = be1 - m1*s1
            float acc = 0.f;
            for (int k = 0; k < 256; k++) {
                const float s1k = g1[k] * rsqrtf(v1[k] + BN_EPS);
                acc += W2[c * 256 + k] * (be1[k] - m1[k] * s1k);
            }
            bias += acc;
        }
        consts[l * 768 + c]       = bias;
        consts[l * 768 + 256 + c] = s;
        consts[l * 768 + 512 + c] = bep[c] - mp[c] * s;
    }
    if (idx < NX) xb[idx] = f2bf(x[idx]);
    if (idx < M) {
        const int tgt = (idx < E) ? eidx[E + idx] : (idx - E);
        atomicAdd(&count[tgt], 1u);
    }
}

__global__ __launch_bounds__(1024) void scan_kernel(
    const unsigned* __restrict__ count, unsigned* __restrict__ cursor, int N)
{
    __shared__ unsigned part[1024];
    const int t = threadIdx.x;
    const int per = (N + 1023) / 1024;
    const int b = t * per;
    unsigned s = 0;
    for (int i = 0; i < per; i++) if (b + i < N) s += count[b + i];
    part[t] = s;
    __syncthreads();
    for (int off = 1; off < 1024; off <<= 1) {
        unsigned v = (t >= off) ? part[t - off] : 0u;
        __syncthreads();
        part[t] += v;
        __syncthreads();
    }
    unsigned run = (t > 0) ? part[t - 1] : 0u;
    for (int i = 0; i < per; i++) {
        if (b + i < N) {
            unsigned c = count[b + i];
            cursor[b + i] = run;
            run += c;
        }
    }
}

__global__ void scatter_kernel(const int* __restrict__ eidx, int E, int M,
                               unsigned* __restrict__ cursor, int* __restrict__ spair)
{
    const int i = blockIdx.x * 256 + threadIdx.x;
    if (i < M) {
        int s, tg;
        if (i < E) { s = eidx[i]; tg = eidx[E + i]; }
        else       { s = tg = i - E; }
        const unsigned pos = atomicAdd(&cursor[tg], 1u);
        int2* p = (int2*)spair;
        p[pos] = make_int2(s, tg);
    }
}

// Fused: gather(copy) -> G1 -> G2 -> segmented max -> atomics
// 512 threads = 8 waves; each wave: 32 outcols x 64 rows (acc[2][4], ~90 VGPR).
// MFMA operands swapped (A=weights, B=messages): reg-quad dim = out channel,
// so epilogue writes are packed ds_write_b64 (4 consecutive cols per lane).
__global__ __launch_bounds__(512, 4) void msg_kernel(
    const unsigned short* __restrict__ xb,
    const int* __restrict__ spair,   // [M] (src,tgt) pairs, sorted by tgt
    int M,
    const unsigned short* __restrict__ W1b,
    const unsigned short* __restrict__ W2b,
    const float* __restrict__ consts,
    unsigned* __restrict__ agg)
{
    __shared__ unsigned short At[64 * 256];   // 32 KiB
    __shared__ int tgt_l[64];

    const int t = threadIdx.x;
    const int base = blockIdx.x * 64;

    // ---- gather: A = [xi | xj] raw bf16 copy (diff folded into W1') ----
    {
        const int row = t >> 3, part = t & 7;
        const int slot = base + row;
        const int c0 = part * 32;
        if (slot < M) {
            const int2 pr = *(const int2*)(spair + 2 * slot);   // (src=x_j, tgt=x_i)
            if (part == 0) tgt_l[row] = pr.y;
            const unsigned short* s = (part < 4)
                ? xb + (size_t)pr.y * 128 + c0            // xi half (k 0..127)
                : xb + (size_t)pr.x * 128 + (c0 - 128);   // xj half (k 128..255)
            #pragma unroll
            for (int w = 0; w < 4; w++)
                *(uint4*)&At[swz(row, c0 + w * 8)] = *(const uint4*)(s + w * 8);
        } else {
            if (part == 0) tgt_l[row] = -1;
            const uint4 z = {0u, 0u, 0u, 0u};
            #pragma unroll
            for (int w = 0; w < 4; w++) *(uint4*)&At[swz(row, c0 + w * 8)] = z;
        }
    }
    __syncthreads();

    const int lane = t & 63;
    const int wv   = t >> 6;          // 0..7
    const int n16  = lane & 15;
    const int qd   = lane >> 4;
    const int wc   = wv * 32;         // this wave's 32 output cols

    const f32x4 vzero = {0.f, 0.f, 0.f, 0.f};
    f32x4 acc[2][4];
    #pragma unroll
    for (int i = 0; i < 2; i++)
        #pragma unroll
        for (int j = 0; j < 4; j++) acc[i][j] = vzero;

    // ---- GEMM1: D[outcol][msgrow], A=W1', B=A-tile ----
    #pragma unroll
    for (int ks = 0; ks < 8; ks++) {
        const int k0 = ks * 32 + qd * 8;
        bf16x8 a[2], b[4];
        #pragma unroll
        for (int ci = 0; ci < 2; ci++)
            a[ci] = *(const bf16x8*)&W1b[(size_t)(wc + ci * 16 + n16) * 256 + k0];
        #pragma unroll
        for (int rj = 0; rj < 4; rj++)
            b[rj] = *(const bf16x8*)&At[swz(rj * 16 + n16, k0)];
        #pragma unroll
        for (int ci = 0; ci < 2; ci++)
            #pragma unroll
            for (int rj = 0; rj < 4; rj++)
                acc[ci][rj] = __builtin_amdgcn_mfma_f32_16x16x32_bf16(a[ci], b[rj], acc[ci][rj], 0, 0, 0);
    }
    __syncthreads();

    // ---- epi1: u1 = relu(z1 + b1) -> bf16, packed b64 writes ----
    {
        const float* B1 = consts;
        #pragma unroll
        for (int ci = 0; ci < 2; ci++) {
            const int col0 = wc + ci * 16 + qd * 4;
            const float4 bb = *(const float4*)&B1[col0];
            #pragma unroll
            for (int rj = 0; rj < 4; rj++) {
                const int row = rj * 16 + n16;
                float v0 = fmaxf(acc[ci][rj][0] + bb.x, 0.f);
                float v1 = fmaxf(acc[ci][rj][1] + bb.y, 0.f);
                float v2 = fmaxf(acc[ci][rj][2] + bb.z, 0.f);
                float v3 = fmaxf(acc[ci][rj][3] + bb.w, 0.f);
                uint2 p = {pk2(v0, v1), pk2(v2, v3)};
                *(uint2*)&At[swz(row, col0)] = p;
                acc[ci][rj] = vzero;
            }
        }
    }
    __syncthreads();

    // ---- GEMM2: A=W2'(BN1-scaled), B=u1 ----
    #pragma unroll
    for (int ks = 0; ks < 8; ks++) {
        const int k0 = ks * 32 + qd * 8;
        bf16x8 a[2], b[4];
        #pragma unroll
        for (int ci = 0; ci < 2; ci++)
            a[ci] = *(const bf16x8*)&W2b[(size_t)(wc + ci * 16 + n16) * 256 + k0];
        #pragma unroll
        for (int rj = 0; rj < 4; rj++)
            b[rj] = *(const bf16x8*)&At[swz(rj * 16 + n16, k0)];
        #pragma unroll
        for (int ci = 0; ci < 2; ci++)
            #pragma unroll
            for (int rj = 0; rj < 4; rj++)
                acc[ci][rj] = __builtin_amdgcn_mfma_f32_16x16x32_bf16(a[ci], b[rj], acc[ci][rj], 0, 0, 0);
    }
    __syncthreads();

    // ---- epi2: h2 = relu(z2 + b2'')*s2 + t2 -> 16-bit keys, packed b64 ----
    {
        const float* B2 = consts + 768;
        const float* S2 = consts + 768 + 256;
        const float* T2 = consts + 768 + 512;
        #pragma unroll
        for (int ci = 0; ci < 2; ci++) {
            const int col0 = wc + ci * 16 + qd * 4;
            const float4 bb = *(const float4*)&B2[col0];
            const float4 ss = *(const float4*)&S2[col0];
            const float4 tt = *(const float4*)&T2[col0];
            #pragma unroll
            for (int rj = 0; rj < 4; rj++) {
                const int row = rj * 16 + n16;
                float v0 = fmaxf(acc[ci][rj][0] + bb.x, 0.f) * ss.x + tt.x;
                float v1 = fmaxf(acc[ci][rj][1] + bb.y, 0.f) * ss.y + tt.y;
                float v2 = fmaxf(acc[ci][rj][2] + bb.z, 0.f) * ss.z + tt.z;
                float v3 = fmaxf(acc[ci][rj][3] + bb.w, 0.f) * ss.w + tt.w;
                uint2 p = {kk2(v0, v1), kk2(v2, v3)};
                *(uint2*)&At[swz(row, col0)] = p;
            }
        }
    }
    __syncthreads();

    // ---- segmented max: wave = 16 rows x 128 cols, lane = 2 cols ----
    {
        const int r0 = (wv & 3) * 16;
        const int cb = (wv >> 2) * 128 + lane * 2;
        const int myt = (lane < 16) ? tgt_l[r0 + lane] : -1;
        int curT = -1;
        unsigned m0 = 0, m1 = 0;
        for (int r = 0; r < 16; r++) {
            const int tg = __shfl(myt, r);            // wave-uniform
            const unsigned k2 = *(const unsigned*)&At[swz(r0 + r, cb)];
            const unsigned k0 = k2 & 0xFFFFu, k1 = k2 >> 16;
            if (tg != curT) {
                if (curT >= 0) {
                    unsigned* p = &agg[(size_t)curT * 256 + cb];
                    atomicMax(p, m0); atomicMax(p + 1, m1);
                }
                curT = tg; m0 = k0; m1 = k1;
            } else {
                m0 = m0 > k0 ? m0 : k0;
                m1 = m1 > k1 ? m1 : k1;
            }
        }
        if (curT >= 0) {
            unsigned* p = &agg[(size_t)curT * 256 + cb];
            atomicMax(p, m0); atomicMax(p + 1, m1);
        }
    }
}

// Final layer: decode agg keys -> GEMM3 -> bias+ReLU+BN -> fp32 out
__global__ __launch_bounds__(256) void out_kernel(
    const unsigned* __restrict__ agg, int N,
    const unsigned short* __restrict__ W3b,
    const float* __restrict__ consts,
    float* __restrict__ out)
{
    __shared__ unsigned short At[32 * 256];

    const int t = threadIdx.x;
    const int base = blockIdx.x * 32;

    {
        const int row = t >> 3, part = t & 7;
        const int node = base + row;
        const int c0 = part * 32;
        if (node < N) {
            const unsigned* ap = agg + (size_t)node * 256 + c0;
            #pragma unroll
            for (int w = 0; w < 4; w++) {
                uint4 a = *(const uint4*)(ap + w * 8);
                uint4 b = *(const uint4*)(ap + w * 8 + 4);
                uint4 p;
                p.x = unb2(a.x, a.y); p.y = unb2(a.z, a.w);
                p.z = unb2(b.x, b.y); p.w = unb2(b.z, b.w);
                *(uint4*)&At[swz(row, c0 + w * 8)] = p;
            }
        } else {
            const uint4 z = {0u, 0u, 0u, 0u};
            #pragma unroll
            for (int w = 0; w < 4; w++) *(uint4*)&At[swz(row, c0 + w * 8)] = z;
        }
    }
    __syncthreads();

    const int lane = t & 63;
    const int wv   = t >> 6;
    const int n16  = lane & 15;
    const int qd   = lane >> 4;
    const int wc   = wv * 64;

    const f32x4 vzero = {0.f, 0.f, 0.f, 0.f};
    f32x4 acc[2][4];
    #pragma unroll
    for (int i = 0; i < 2; i++)
        #pragma unroll
        for (int j = 0; j < 4; j++) acc[i][j] = vzero;

    #pragma unroll
    for (int ks = 0; ks < 8; ks++) {
        const int k0 = ks * 32 + qd * 8;
        bf16x8 a[2];
        #pragma unroll
        for (int ri = 0; ri < 2; ri++)
            a[ri] = *(const bf16x8*)&At[swz(ri * 16 + n16, k0)];
        #pragma unroll
        for (int ci = 0; ci < 4; ci++) {
            bf16x8 b = *(const bf16x8*)&W3b[(size_t)(wc + ci * 16 + n16) * 256 + k0];
            #pragma unroll
            for (int ri = 0; ri < 2; ri++)
                acc[ri][ci] = __builtin_amdgcn_mfma_f32_16x16x32_bf16(a[ri], b, acc[ri][ci], 0, 0, 0);
        }
    }

    {
        const float* B3 = consts + 1536;
        const float* S3 = consts + 1536 + 256;
        const float* T3 = consts + 1536 + 512;
        #pragma unroll
        for (int ci = 0; ci < 4; ci++) {
            const int col = wc + ci * 16 + n16;
            const float bb = B3[col], ss = S3[col], tt = T3[col];
            #pragma unroll
            for (int ri = 0; ri < 2; ri++) {
                #pragma unroll
                for (int r = 0; r < 4; r++) {
                    const int row = ri * 16 + qd * 4 + r;
                    const int node = base + row;
                    if (node < N) {
                        float v = fmaxf(acc[ri][ci][r] + bb, 0.f) * ss + tt;
                        out[(size_t)node * 256 + col] = v;
                    }
                }
            }
        }
    }
}

extern "C" void kernel_launch(void* const* d_in, const int* in_sizes, int n_in,
                              void* d_out, int out_size, void* d_ws, size_t ws_size,
                              hipStream_t stream)
{
    const float* x  = (const float*)d_in[0];
    const int* eidx = (const int*)d_in[1];
    const int N = in_sizes[0] / 128;
    const int NX = in_sizes[0];
    const int E = in_sizes[1] / 2;
    const int M = E + N;

    char* ws = (char*)d_ws;
    unsigned short* W1b = (unsigned short*)(ws);
    unsigned short* W2b = (unsigned short*)(ws + 131072);
    unsigned short* W3b = (unsigned short*)(ws + 262144);
    float* consts       = (float*)(ws + 393216);                 // 2304 f32
    size_t off = 402432;
    unsigned short* xb  = (unsigned short*)(ws + off); off += (size_t)NX * 2;
    unsigned* agg       = (unsigned*)(ws + off);       off += (size_t)N * 256 * 4;
    unsigned* count     = (unsigned*)(ws + off);       off += (size_t)N * 4;
    unsigned* cursor    = (unsigned*)(ws + off);       off += (size_t)N * 4;
    int* spair          = (int*)(ws + off);            // M int2

    hipMemsetAsync(agg, 0, (size_t)N * 256 * 4, stream);
    hipMemsetAsync(count, 0, (size_t)N * 4, stream);

    int work = NX;
    if (M > work) work = M;
    if (65536 > work) work = 65536;
    hipLaunchKernelGGL(prep_kernel, dim3((work + 255) / 256), dim3(256), 0, stream,
        x, eidx, E, M, NX,
        (const float*)d_in[2], (const float*)d_in[8], (const float*)d_in[14],
        (const float*)d_in[3], (const float*)d_in[4], (const float*)d_in[5],
        (const float*)d_in[6], (const float*)d_in[7],
        (const float*)d_in[9], (const float*)d_in[10], (const float*)d_in[11],
        (const float*)d_in[12], (const float*)d_in[13],
        (const float*)d_in[15], (const float*)d_in[16], (const float*)d_in[17],
        (const float*)d_in[18], (const float*)d_in[19],
        W1b, W2b, W3b, consts, xb, count);

    hipLaunchKernelGGL(scan_kernel, dim3(1), dim3(1024), 0, stream,
        count, cursor, N);
    hipLaunchKernelGGL(scatter_kernel, dim3((M + 255) / 256), dim3(256), 0, stream,
        eidx, E, M, cursor, spair);

    hipLaunchKernelGGL(msg_kernel, dim3((M + 63) / 64), dim3(512), 0, stream,
        xb, spair, M, W1b, W2b, consts, agg);

    hipLaunchKernelGGL(out_kernel, dim3((N + 31) / 32), dim3(256), 0, stream,
        agg, N, W3b, consts, (float*)d_out);
}

// Round 6
// 517.285 us; speedup vs baseline: 2.1967x; 1.2387x over previous
//
#include <hip/hip_runtime.h>
#include <stdint.h>

#define BN_EPS 1e-5f

typedef __bf16 bf16x8 __attribute__((ext_vector_type(8)));
typedef float  f32x4  __attribute__((ext_vector_type(4)));

__device__ __forceinline__ unsigned short f2bf(float f) {
    unsigned u = __float_as_uint(f);
    unsigned r = (u + 0x7FFFu + ((u >> 16) & 1u)) >> 16;
    return (unsigned short)r;
}
__device__ __forceinline__ unsigned pk2(float a, float b) {
    return (unsigned)f2bf(a) | ((unsigned)f2bf(b) << 16);
}
// packed: relu(p + q) on bf16 pairs, fp32 math, RNE repack
__device__ __forceinline__ unsigned ar2(unsigned p, unsigned q) {
    float pl = __uint_as_float(p << 16), ql = __uint_as_float(q << 16);
    float ph = __uint_as_float(p & 0xFFFF0000u), qh = __uint_as_float(q & 0xFFFF0000u);
    return pk2(fmaxf(pl + ql, 0.f), fmaxf(ph + qh, 0.f));
}
// order-preserving bf16 -> 16-bit key (monotone); 0 < every real key
__device__ __forceinline__ unsigned short bfkey(unsigned short h) {
    return (h & 0x8000u) ? (unsigned short)(~h) : (unsigned short)(h | 0x8000u);
}
__device__ __forceinline__ unsigned short unbfkey(unsigned short k) {
    return (k & 0x8000u) ? (unsigned short)(k & 0x7FFFu) : (unsigned short)(~k);
}
__device__ __forceinline__ unsigned unb2(unsigned k0, unsigned k1) {
    return (unsigned)unbfkey((unsigned short)k0)
         | ((unsigned)unbfkey((unsigned short)k1) << 16);
}
__device__ __forceinline__ unsigned kk2(float a, float b) {
    return (unsigned)bfkey(f2bf(a)) | ((unsigned)bfkey(f2bf(b)) << 16);
}
// LDS swizzle, 256-col ushort tile: 16B blocks XOR'd by row&7; rows 16B-aligned
__device__ __forceinline__ int swz(int row, int k) {
    const int blk = k >> 3;
    const int sb = (blk & 24) | ((blk ^ row) & 7);
    return (row << 8) + (sb << 3) + (k & 7);
}
// LDS swizzle, 128-col ushort tile
__device__ __forceinline__ int swz128(int row, int k) {
    const int blk = k >> 3;
    const int sb = (blk & 8) | ((blk ^ row) & 7);
    return (row << 7) + (sb << 3) + (k & 7);
}

// prep: W1' fold (edge-diff), W2' fold (BN1 scale), b2'' matvec, W3 convert,
// BN consts, x->bf16, target histogram
__global__ void prep_kernel(
    const float* __restrict__ x, const int* __restrict__ eidx,
    int E, int M, int NX,
    const float* __restrict__ W1, const float* __restrict__ W2, const float* __restrict__ W3,
    const float* __restrict__ b1, const float* __restrict__ g1, const float* __restrict__ be1,
    const float* __restrict__ m1, const float* __restrict__ v1,
    const float* __restrict__ b2, const float* __restrict__ g2, const float* __restrict__ be2,
    const float* __restrict__ m2, const float* __restrict__ v2,
    const float* __restrict__ b3, const float* __restrict__ g3, const float* __restrict__ be3,
    const float* __restrict__ m3, const float* __restrict__ v3,
    unsigned short* __restrict__ W1b, unsigned short* __restrict__ W2b,
    unsigned short* __restrict__ W3b, float* __restrict__ consts,
    unsigned short* __restrict__ xb, unsigned* __restrict__ count)
{
    const int idx = blockIdx.x * 256 + threadIdx.x;
    if (idx < 65536) {
        const int row = idx >> 8, c = idx & 255;
        // W1' = [W1a - W1b | W1b]  (z1 = xi@(W1a-W1b)^T + xj@W1b^T)
        float w1v = (c < 128) ? (W1[row * 256 + c] - W1[row * 256 + c + 128])
                              : W1[row * 256 + c];
        W1b[idx] = f2bf(w1v);
        // W2' = W2 * s1  (fold BN1 scale into W2 input channels)
        const float s1c = g1[c] * rsqrtf(v1[c] + BN_EPS);
        W2b[idx] = f2bf(W2[idx] * s1c);
        W3b[idx] = f2bf(W3[idx]);
    }
    if (idx < 768) {
        const int l = idx >> 8, c = idx & 255;
        const float* bp  = l == 0 ? b1  : (l == 1 ? b2  : b3);
        const float* gp  = l == 0 ? g1  : (l == 1 ? g2  : g3);
        const float* bep = l == 0 ? be1 : (l == 1 ? be2 : be3);
        const float* mp  = l == 0 ? m1  : (l == 1 ? m2  : m3);
        const float* vp  = l == 0 ? v1  : (l == 1 ? v2  : v3);
        const float s = gp[c] * rsqrtf(vp[c] + BN_EPS);
        float bias = bp[c];
        if (l == 1) {
            // b2'' = b2 + W2 @ t1; t1 = be1 - m1*s1
            float acc = 0.f;
            for (int k = 0; k < 256; k++) {
                const float s1k = g1[k] * rsqrtf(v1[k] + BN_EPS);
                acc += W2[c * 256 + k] * (be1[k] - m1[k] * s1k);
            }
            bias += acc;
        }
        consts[l * 768 + c]       = bias;
        consts[l * 768 + 256 + c] = s;
        consts[l * 768 + 512 + c] = bep[c] - mp[c] * s;
    }
    if (idx < NX) xb[idx] = f2bf(x[idx]);
    if (idx < M) {
        const int tgt = (idx < E) ? eidx[E + idx] : (idx - E);
        atomicAdd(&count[tgt], 1u);
    }
}

// pq: P' = X@(W1a-W1b)^T + b1, Q = X@W1b^T  (per-node layer-1 precompute)
__global__ __launch_bounds__(512) void pq_kernel(
    const unsigned short* __restrict__ xb, int N,
    const unsigned short* __restrict__ W1b,   // 256x256 [Wi|Wj] bf16
    const float* __restrict__ consts,         // b1 at [0..255]
    unsigned short* __restrict__ Pb, unsigned short* __restrict__ Qb)
{
    __shared__ unsigned short Xs[64 * 128];   // 16 KiB

    const int t = threadIdx.x;
    const int base = blockIdx.x * 64;

    {
        const int row = t >> 3, part = t & 7;
        const int node = base + row;
        const int c0 = part * 16;
        if (node < N) {
            const unsigned short* s = xb + (size_t)node * 128 + c0;
            *(uint4*)&Xs[swz128(row, c0)]     = *(const uint4*)(s);
            *(uint4*)&Xs[swz128(row, c0 + 8)] = *(const uint4*)(s + 8);
        } else {
            const uint4 z = {0u, 0u, 0u, 0u};
            *(uint4*)&Xs[swz128(row, c0)]     = z;
            *(uint4*)&Xs[swz128(row, c0 + 8)] = z;
        }
    }
    __syncthreads();

    const int lane = t & 63;
    const int wv   = t >> 6;
    const int n16  = lane & 15;
    const int qd   = lane >> 4;
    const int wc   = wv * 32;   // 32 outcols per wave

    const f32x4 vzero = {0.f, 0.f, 0.f, 0.f};

    // two passes: ph=0 -> P' (Wi half, +b1), ph=1 -> Q (Wj half)
    #pragma unroll
    for (int ph = 0; ph < 2; ph++) {
        f32x4 acc[2][4];
        #pragma unroll
        for (int i = 0; i < 2; i++)
            #pragma unroll
            for (int j = 0; j < 4; j++) acc[i][j] = vzero;

        #pragma unroll
        for (int ks = 0; ks < 4; ks++) {
            const int k0 = ks * 32 + qd * 8;
            bf16x8 a[2], b[4];
            #pragma unroll
            for (int ci = 0; ci < 2; ci++)
                a[ci] = *(const bf16x8*)&W1b[(size_t)(wc + ci * 16 + n16) * 256 + ph * 128 + k0];
            #pragma unroll
            for (int rj = 0; rj < 4; rj++)
                b[rj] = *(const bf16x8*)&Xs[swz128(rj * 16 + n16, k0)];
            #pragma unroll
            for (int ci = 0; ci < 2; ci++)
                #pragma unroll
                for (int rj = 0; rj < 4; rj++)
                    acc[ci][rj] = __builtin_amdgcn_mfma_f32_16x16x32_bf16(a[ci], b[rj], acc[ci][rj], 0, 0, 0);
        }

        unsigned short* dst = ph == 0 ? Pb : Qb;
        #pragma unroll
        for (int ci = 0; ci < 2; ci++) {
            const int col0 = wc + ci * 16 + qd * 4;
            float4 bb = {0.f, 0.f, 0.f, 0.f};
            if (ph == 0) bb = *(const float4*)&consts[col0];
            #pragma unroll
            for (int rj = 0; rj < 4; rj++) {
                const int node = base + rj * 16 + n16;
                if (node < N) {
                    uint2 p = {pk2(acc[ci][rj][0] + bb.x, acc[ci][rj][1] + bb.y),
                               pk2(acc[ci][rj][2] + bb.z, acc[ci][rj][3] + bb.w)};
                    *(uint2*)(dst + (size_t)node * 256 + col0) = p;
                }
            }
        }
    }
}

__global__ __launch_bounds__(1024) void scan_kernel(
    const unsigned* __restrict__ count, unsigned* __restrict__ cursor, int N)
{
    __shared__ unsigned part[1024];
    const int t = threadIdx.x;
    const int per = (N + 1023) / 1024;
    const int b = t * per;
    unsigned s = 0;
    for (int i = 0; i < per; i++) if (b + i < N) s += count[b + i];
    part[t] = s;
    __syncthreads();
    for (int off = 1; off < 1024; off <<= 1) {
        unsigned v = (t >= off) ? part[t - off] : 0u;
        __syncthreads();
        part[t] += v;
        __syncthreads();
    }
    unsigned run = (t > 0) ? part[t - 1] : 0u;
    for (int i = 0; i < per; i++) {
        if (b + i < N) {
            unsigned c = count[b + i];
            cursor[b + i] = run;
            run += c;
        }
    }
}

__global__ void scatter_kernel(const int* __restrict__ eidx, int E, int M,
                               unsigned* __restrict__ cursor, int* __restrict__ spair)
{
    const int i = blockIdx.x * 256 + threadIdx.x;
    if (i < M) {
        int s, tg;
        if (i < E) { s = eidx[i]; tg = eidx[E + i]; }
        else       { s = tg = i - E; }
        const unsigned pos = atomicAdd(&cursor[tg], 1u);
        int2* p = (int2*)spair;
        p[pos] = make_int2(s, tg);
    }
}

// Fused: u1 = relu(P'[tgt]+Q[src]) -> GEMM2 -> epi2 -> segmented max -> atomics
// (GEMM1 eliminated via per-node P/Q precompute.)
__global__ __launch_bounds__(512) void msg_kernel(
    const unsigned short* __restrict__ Pb,
    const unsigned short* __restrict__ Qb,
    const int* __restrict__ spair,   // [M] (src,tgt) pairs, sorted by tgt
    int M,
    const unsigned short* __restrict__ W2b,
    const float* __restrict__ consts,
    unsigned* __restrict__ agg)
{
    __shared__ unsigned short At[64 * 256];   // 32 KiB
    __shared__ int tgt_l[64];

    const int t = threadIdx.x;
    const int base = blockIdx.x * 64;

    // ---- gather+L1: u1 = relu(P'[tgt] + Q[src]) straight into LDS ----
    {
        const int row = t >> 3, part = t & 7;
        const int slot = base + row;
        const int c0 = part * 32;
        if (slot < M) {
            const int2 pr = *(const int2*)(spair + 2 * slot);   // (src, tgt)
            if (part == 0) tgt_l[row] = pr.y;
            const unsigned short* Pp = Pb + (size_t)pr.y * 256 + c0;
            const unsigned short* Qp = Qb + (size_t)pr.x * 256 + c0;
            uint4 P4[4], Q4[4];
            #pragma unroll
            for (int w = 0; w < 4; w++) P4[w] = *(const uint4*)(Pp + w * 8);
            #pragma unroll
            for (int w = 0; w < 4; w++) Q4[w] = *(const uint4*)(Qp + w * 8);
            #pragma unroll
            for (int w = 0; w < 4; w++) {
                uint4 u;
                u.x = ar2(P4[w].x, Q4[w].x);
                u.y = ar2(P4[w].y, Q4[w].y);
                u.z = ar2(P4[w].z, Q4[w].z);
                u.w = ar2(P4[w].w, Q4[w].w);
                *(uint4*)&At[swz(row, c0 + w * 8)] = u;
            }
        } else {
            if (part == 0) tgt_l[row] = -1;
            const uint4 z = {0u, 0u, 0u, 0u};
            #pragma unroll
            for (int w = 0; w < 4; w++) *(uint4*)&At[swz(row, c0 + w * 8)] = z;
        }
    }
    __syncthreads();

    const int lane = t & 63;
    const int wv   = t >> 6;          // 0..7
    const int n16  = lane & 15;
    const int qd   = lane >> 4;
    const int wc   = wv * 32;         // this wave's 32 output cols

    const f32x4 vzero = {0.f, 0.f, 0.f, 0.f};
    f32x4 acc[2][4];
    #pragma unroll
    for (int i = 0; i < 2; i++)
        #pragma unroll
        for (int j = 0; j < 4; j++) acc[i][j] = vzero;

    // ---- GEMM2: A=W2'(BN1-scaled), B=u1 ----
    #pragma unroll
    for (int ks = 0; ks < 8; ks++) {
        const int k0 = ks * 32 + qd * 8;
        bf16x8 a[2], b[4];
        #pragma unroll
        for (int ci = 0; ci < 2; ci++)
            a[ci] = *(const bf16x8*)&W2b[(size_t)(wc + ci * 16 + n16) * 256 + k0];
        #pragma unroll
        for (int rj = 0; rj < 4; rj++)
            b[rj] = *(const bf16x8*)&At[swz(rj * 16 + n16, k0)];
        #pragma unroll
        for (int ci = 0; ci < 2; ci++)
            #pragma unroll
            for (int rj = 0; rj < 4; rj++)
                acc[ci][rj] = __builtin_amdgcn_mfma_f32_16x16x32_bf16(a[ci], b[rj], acc[ci][rj], 0, 0, 0);
    }
    __syncthreads();

    // ---- epi2: h2 = relu(z2 + b2'')*s2 + t2 -> 16-bit keys, packed b64 ----
    {
        const float* B2 = consts + 768;
        const float* S2 = consts + 768 + 256;
        const float* T2 = consts + 768 + 512;
        #pragma unroll
        for (int ci = 0; ci < 2; ci++) {
            const int col0 = wc + ci * 16 + qd * 4;
            const float4 bb = *(const float4*)&B2[col0];
            const float4 ss = *(const float4*)&S2[col0];
            const float4 tt = *(const float4*)&T2[col0];
            #pragma unroll
            for (int rj = 0; rj < 4; rj++) {
                const int row = rj * 16 + n16;
                float v0 = fmaxf(acc[ci][rj][0] + bb.x, 0.f) * ss.x + tt.x;
                float v1 = fmaxf(acc[ci][rj][1] + bb.y, 0.f) * ss.y + tt.y;
                float v2 = fmaxf(acc[ci][rj][2] + bb.z, 0.f) * ss.z + tt.z;
                float v3 = fmaxf(acc[ci][rj][3] + bb.w, 0.f) * ss.w + tt.w;
                uint2 p = {kk2(v0, v1), kk2(v2, v3)};
                *(uint2*)&At[swz(row, col0)] = p;
            }
        }
    }
    __syncthreads();

    // ---- segmented max: wave = 16 rows x 128 cols, lane = 2 cols ----
    {
        const int r0 = (wv & 3) * 16;
        const int cb = (wv >> 2) * 128 + lane * 2;
        const int myt = (lane < 16) ? tgt_l[r0 + lane] : -1;
        int curT = -1;
        unsigned m0 = 0, m1 = 0;
        for (int r = 0; r < 16; r++) {
            const int tg = __shfl(myt, r);            // wave-uniform
            const unsigned k2 = *(const unsigned*)&At[swz(r0 + r, cb)];
            const unsigned k0 = k2 & 0xFFFFu, k1 = k2 >> 16;
            if (tg != curT) {
                if (curT >= 0) {
                    unsigned* p = &agg[(size_t)curT * 256 + cb];
                    atomicMax(p, m0); atomicMax(p + 1, m1);
                }
                curT = tg; m0 = k0; m1 = k1;
            } else {
                m0 = m0 > k0 ? m0 : k0;
                m1 = m1 > k1 ? m1 : k1;
            }
        }
        if (curT >= 0) {
            unsigned* p = &agg[(size_t)curT * 256 + cb];
            atomicMax(p, m0); atomicMax(p + 1, m1);
        }
    }
}

// Final layer: decode agg keys -> GEMM3 -> bias+ReLU+BN -> fp32 out
__global__ __launch_bounds__(256) void out_kernel(
    const unsigned* __restrict__ agg, int N,
    const unsigned short* __restrict__ W3b,
    const float* __restrict__ consts,
    float* __restrict__ out)
{
    __shared__ unsigned short At[32 * 256];

    const int t = threadIdx.x;
    const int base = blockIdx.x * 32;

    {
        const int row = t >> 3, part = t & 7;
        const int node = base + row;
        const int c0 = part * 32;
        if (node < N) {
            const unsigned* ap = agg + (size_t)node * 256 + c0;
            #pragma unroll
            for (int w = 0; w < 4; w++) {
                uint4 a = *(const uint4*)(ap + w * 8);
                uint4 b = *(const uint4*)(ap + w * 8 + 4);
                uint4 p;
                p.x = unb2(a.x, a.y); p.y = unb2(a.z, a.w);
                p.z = unb2(b.x, b.y); p.w = unb2(b.z, b.w);
                *(uint4*)&At[swz(row, c0 + w * 8)] = p;
            }
        } else {
            const uint4 z = {0u, 0u, 0u, 0u};
            #pragma unroll
            for (int w = 0; w < 4; w++) *(uint4*)&At[swz(row, c0 + w * 8)] = z;
        }
    }
    __syncthreads();

    const int lane = t & 63;
    const int wv   = t >> 6;
    const int n16  = lane & 15;
    const int qd   = lane >> 4;
    const int wc   = wv * 64;

    const f32x4 vzero = {0.f, 0.f, 0.f, 0.f};
    f32x4 acc[2][4];
    #pragma unroll
    for (int i = 0; i < 2; i++)
        #pragma unroll
        for (int j = 0; j < 4; j++) acc[i][j] = vzero;

    #pragma unroll
    for (int ks = 0; ks < 8; ks++) {
        const int k0 = ks * 32 + qd * 8;
        bf16x8 a[2];
        #pragma unroll
        for (int ri = 0; ri < 2; ri++)
            a[ri] = *(const bf16x8*)&At[swz(ri * 16 + n16, k0)];
        #pragma unroll
        for (int ci = 0; ci < 4; ci++) {
            bf16x8 b = *(const bf16x8*)&W3b[(size_t)(wc + ci * 16 + n16) * 256 + k0];
            #pragma unroll
            for (int ri = 0; ri < 2; ri++)
                acc[ri][ci] = __builtin_amdgcn_mfma_f32_16x16x32_bf16(a[ri], b, acc[ri][ci], 0, 0, 0);
        }
    }

    {
        const float* B3 = consts + 1536;
        const float* S3 = consts + 1536 + 256;
        const float* T3 = consts + 1536 + 512;
        #pragma unroll
        for (int ci = 0; ci < 4; ci++) {
            const int col = wc + ci * 16 + n16;
            const float bb = B3[col], ss = S3[col], tt = T3[col];
            #pragma unroll
            for (int ri = 0; ri < 2; ri++) {
                #pragma unroll
                for (int r = 0; r < 4; r++) {
                    const int row = ri * 16 + qd * 4 + r;
                    const int node = base + row;
                    if (node < N) {
                        float v = fmaxf(acc[ri][ci][r] + bb, 0.f) * ss + tt;
                        out[(size_t)node * 256 + col] = v;
                    }
                }
            }
        }
    }
}

extern "C" void kernel_launch(void* const* d_in, const int* in_sizes, int n_in,
                              void* d_out, int out_size, void* d_ws, size_t ws_size,
                              hipStream_t stream)
{
    const float* x  = (const float*)d_in[0];
    const int* eidx = (const int*)d_in[1];
    const int N = in_sizes[0] / 128;
    const int NX = in_sizes[0];
    const int E = in_sizes[1] / 2;
    const int M = E + N;

    char* ws = (char*)d_ws;
    unsigned short* W1b = (unsigned short*)(ws);
    unsigned short* W2b = (unsigned short*)(ws + 131072);
    unsigned short* W3b = (unsigned short*)(ws + 262144);
    float* consts       = (float*)(ws + 393216);                 // 2304 f32
    size_t off = 402432;
    unsigned short* xb  = (unsigned short*)(ws + off); off += (size_t)NX * 2;
    unsigned* agg       = (unsigned*)(ws + off);       off += (size_t)N * 256 * 4;
    unsigned* count     = (unsigned*)(ws + off);       off += (size_t)N * 4;
    unsigned* cursor    = (unsigned*)(ws + off);       off += (size_t)N * 4;
    int* spair          = (int*)(ws + off);            off += (size_t)M * 8;
    unsigned short* Pb  = (unsigned short*)(ws + off); off += (size_t)N * 256 * 2;
    unsigned short* Qb  = (unsigned short*)(ws + off);

    hipMemsetAsync(agg, 0, (size_t)N * 256 * 4, stream);
    hipMemsetAsync(count, 0, (size_t)N * 4, stream);

    int work = NX;
    if (M > work) work = M;
    if (65536 > work) work = 65536;
    hipLaunchKernelGGL(prep_kernel, dim3((work + 255) / 256), dim3(256), 0, stream,
        x, eidx, E, M, NX,
        (const float*)d_in[2], (const float*)d_in[8], (const float*)d_in[14],
        (const float*)d_in[3], (const float*)d_in[4], (const float*)d_in[5],
        (const float*)d_in[6], (const float*)d_in[7],
        (const float*)d_in[9], (const float*)d_in[10], (const float*)d_in[11],
        (const float*)d_in[12], (const float*)d_in[13],
        (const float*)d_in[15], (const float*)d_in[16], (const float*)d_in[17],
        (const float*)d_in[18], (const float*)d_in[19],
        W1b, W2b, W3b, consts, xb, count);

    hipLaunchKernelGGL(pq_kernel, dim3((N + 63) / 64), dim3(512), 0, stream,
        xb, N, W1b, consts, Pb, Qb);

    hipLaunchKernelGGL(scan_kernel, dim3(1), dim3(1024), 0, stream,
        count, cursor, N);
    hipLaunchKernelGGL(scatter_kernel, dim3((M + 255) / 256), dim3(256), 0, stream,
        eidx, E, M, cursor, spair);

    hipLaunchKernelGGL(msg_kernel, dim3((M + 63) / 64), dim3(512), 0, stream,
        Pb, Qb, spair, M, W2b, consts, agg);

    hipLaunchKernelGGL(out_kernel, dim3((N + 31) / 32), dim3(256), 0, stream,
        agg, N, W3b, consts, (float*)d_out);
}

// Round 7
// 490.936 us; speedup vs baseline: 2.3146x; 1.0537x over previous
//
#include <hip/hip_runtime.h>
#include <stdint.h>

#define BN_EPS 1e-5f

typedef __bf16 bf16x8 __attribute__((ext_vector_type(8)));
typedef __bf16 bf16x2 __attribute__((ext_vector_type(2)));
typedef float  f32x4  __attribute__((ext_vector_type(4)));
typedef float  f32x2  __attribute__((ext_vector_type(2)));

__device__ __forceinline__ unsigned short f2bf(float f) {
    unsigned u = __float_as_uint(f);
    unsigned r = (u + 0x7FFFu + ((u >> 16) & 1u)) >> 16;
    return (unsigned short)r;
}
// HW packed f32x2 -> bf16x2 (v_cvt_pk_bf16_f32 on gfx950), RNE
__device__ __forceinline__ unsigned pkb(float a, float b) {
    f32x2 f; f.x = a; f.y = b;
    bf16x2 h = __builtin_convertvector(f, bf16x2);
    return *(unsigned*)&h;
}
// packed relu(p + q) on bf16 pairs: unpack, v_pk_add_f32, max, HW repack
__device__ __forceinline__ unsigned ar2(unsigned p, unsigned q) {
    f32x2 a, b;
    a.x = __uint_as_float(p << 16);
    a.y = __uint_as_float(p & 0xFFFF0000u);
    b.x = __uint_as_float(q << 16);
    b.y = __uint_as_float(q & 0xFFFF0000u);
    f32x2 s = a + b;
    return pkb(fmaxf(s.x, 0.f), fmaxf(s.y, 0.f));
}
// LDS swizzle, 256-col ushort tile: 16B blocks XOR'd by row&7; rows 16B-aligned
__device__ __forceinline__ int swz(int row, int k) {
    const int blk = k >> 3;
    const int sb = (blk & 24) | ((blk ^ row) & 7);
    return (row << 8) + (sb << 3) + (k & 7);
}
// LDS swizzle, 128-col ushort tile
__device__ __forceinline__ int swz128(int row, int k) {
    const int blk = k >> 3;
    const int sb = (blk & 8) | ((blk ^ row) & 7);
    return (row << 7) + (sb << 3) + (k & 7);
}

// prep: W1' fold (edge-diff), W2' fold (BN1 scale), W3' fold (BN2 scale),
// b2'' and b3' matvecs, sign masks, BN consts, x->bf16, target histogram
__global__ void prep_kernel(
    const float* __restrict__ x, const int* __restrict__ eidx,
    int E, int M, int NX,
    const float* __restrict__ W1, const float* __restrict__ W2, const float* __restrict__ W3,
    const float* __restrict__ b1, const float* __restrict__ g1, const float* __restrict__ be1,
    const float* __restrict__ m1, const float* __restrict__ v1,
    const float* __restrict__ b2, const float* __restrict__ g2, const float* __restrict__ be2,
    const float* __restrict__ m2, const float* __restrict__ v2,
    const float* __restrict__ b3, const float* __restrict__ g3, const float* __restrict__ be3,
    const float* __restrict__ m3, const float* __restrict__ v3,
    unsigned short* __restrict__ W1b, unsigned short* __restrict__ W2b,
    unsigned short* __restrict__ W3b, float* __restrict__ consts,
    unsigned* __restrict__ mask2,
    unsigned short* __restrict__ xb, unsigned* __restrict__ count)
{
    const int idx = blockIdx.x * 256 + threadIdx.x;
    if (idx < 65536) {
        const int row = idx >> 8, c = idx & 255;
        // W1' = [W1a - W1b | W1b]  (z1 = xi@(W1a-W1b)^T + xj@W1b^T)
        float w1v = (c < 128) ? (W1[row * 256 + c] - W1[row * 256 + c + 128])
                              : W1[row * 256 + c];
        W1b[idx] = f2bf(w1v);
        // W2' = W2 * s1  (fold BN1 scale into W2 input channels)
        const float s1c = g1[c] * rsqrtf(v1[c] + BN_EPS);
        W2b[idx] = f2bf(W2[idx] * s1c);
        // W3' = W3 * s2  (fold BN2 scale into W3 input channels)
        const float s2c = g2[c] * rsqrtf(v2[c] + BN_EPS);
        W3b[idx] = f2bf(W3[idx] * s2c);
    }
    if (idx < 128) {
        // per-column-pair sign masks for BN2 scale (max<->min flip when s2<0)
        const float sa = g2[2 * idx]     * rsqrtf(v2[2 * idx]     + BN_EPS);
        const float sb = g2[2 * idx + 1] * rsqrtf(v2[2 * idx + 1] + BN_EPS);
        mask2[idx] = (sa < 0.f ? 0xFFFFu : 0u) | ((sb < 0.f ? 0xFFFFu : 0u) << 16);
    }
    if (idx < 768) {
        const int l = idx >> 8, c = idx & 255;
        const float* bp  = l == 0 ? b1  : (l == 1 ? b2  : b3);
        const float* gp  = l == 0 ? g1  : (l == 1 ? g2  : g3);
        const float* bep = l == 0 ? be1 : (l == 1 ? be2 : be3);
        const float* mp  = l == 0 ? m1  : (l == 1 ? m2  : m3);
        const float* vp  = l == 0 ? v1  : (l == 1 ? v2  : v3);
        const float s = gp[c] * rsqrtf(vp[c] + BN_EPS);
        float bias = bp[c];
        if (l == 1) {
            // b2'' = b2 + W2 @ t1; t1 = be1 - m1*s1
            float acc = 0.f;
            for (int k = 0; k < 256; k++) {
                const float s1k = g1[k] * rsqrtf(v1[k] + BN_EPS);
                acc += W2[c * 256 + k] * (be1[k] - m1[k] * s1k);
            }
            bias += acc;
        } else if (l == 2) {
            // b3' = b3 + W3 @ t2; t2 = be2 - m2*s2
            float acc = 0.f;
            for (int k = 0; k < 256; k++) {
                const float s2k = g2[k] * rsqrtf(v2[k] + BN_EPS);
                acc += W3[c * 256 + k] * (be2[k] - m2[k] * s2k);
            }
            bias += acc;
        }
        consts[l * 768 + c]       = bias;
        consts[l * 768 + 256 + c] = s;
        consts[l * 768 + 512 + c] = bep[c] - mp[c] * s;
    }
    if (idx < NX) xb[idx] = f2bf(x[idx]);
    if (idx < M) {
        const int tgt = (idx < E) ? eidx[E + idx] : (idx - E);
        atomicAdd(&count[tgt], 1u);
    }
}

// pq: P' = X@(W1a-W1b)^T + b1, Q = X@W1b^T  (per-node layer-1 precompute)
__global__ __launch_bounds__(512) void pq_kernel(
    const unsigned short* __restrict__ xb, int N,
    const unsigned short* __restrict__ W1b,   // 256x256 [Wi|Wj] bf16
    const float* __restrict__ consts,         // b1 at [0..255]
    unsigned short* __restrict__ Pb, unsigned short* __restrict__ Qb)
{
    __shared__ unsigned short Xs[64 * 128];   // 16 KiB

    const int t = threadIdx.x;
    const int base = blockIdx.x * 64;

    {
        const int row = t >> 3, part = t & 7;
        const int node = base + row;
        const int c0 = part * 16;
        if (node < N) {
            const unsigned short* s = xb + (size_t)node * 128 + c0;
            *(uint4*)&Xs[swz128(row, c0)]     = *(const uint4*)(s);
            *(uint4*)&Xs[swz128(row, c0 + 8)] = *(const uint4*)(s + 8);
        } else {
            const uint4 z = {0u, 0u, 0u, 0u};
            *(uint4*)&Xs[swz128(row, c0)]     = z;
            *(uint4*)&Xs[swz128(row, c0 + 8)] = z;
        }
    }
    __syncthreads();

    const int lane = t & 63;
    const int wv   = t >> 6;
    const int n16  = lane & 15;
    const int qd   = lane >> 4;
    const int wc   = wv * 32;   // 32 outcols per wave

    const f32x4 vzero = {0.f, 0.f, 0.f, 0.f};

    // two passes: ph=0 -> P' (Wi half, +b1), ph=1 -> Q (Wj half)
    #pragma unroll
    for (int ph = 0; ph < 2; ph++) {
        f32x4 acc[2][4];
        #pragma unroll
        for (int i = 0; i < 2; i++)
            #pragma unroll
            for (int j = 0; j < 4; j++) acc[i][j] = vzero;

        #pragma unroll
        for (int ks = 0; ks < 4; ks++) {
            const int k0 = ks * 32 + qd * 8;
            bf16x8 a[2], b[4];
            #pragma unroll
            for (int ci = 0; ci < 2; ci++)
                a[ci] = *(const bf16x8*)&W1b[(size_t)(wc + ci * 16 + n16) * 256 + ph * 128 + k0];
            #pragma unroll
            for (int rj = 0; rj < 4; rj++)
                b[rj] = *(const bf16x8*)&Xs[swz128(rj * 16 + n16, k0)];
            #pragma unroll
            for (int ci = 0; ci < 2; ci++)
                #pragma unroll
                for (int rj = 0; rj < 4; rj++)
                    acc[ci][rj] = __builtin_amdgcn_mfma_f32_16x16x32_bf16(a[ci], b[rj], acc[ci][rj], 0, 0, 0);
        }

        unsigned short* dst = ph == 0 ? Pb : Qb;
        #pragma unroll
        for (int ci = 0; ci < 2; ci++) {
            const int col0 = wc + ci * 16 + qd * 4;
            float4 bb = {0.f, 0.f, 0.f, 0.f};
            if (ph == 0) bb = *(const float4*)&consts[col0];
            #pragma unroll
            for (int rj = 0; rj < 4; rj++) {
                const int node = base + rj * 16 + n16;
                if (node < N) {
                    uint2 p = {pkb(acc[ci][rj][0] + bb.x, acc[ci][rj][1] + bb.y),
                               pkb(acc[ci][rj][2] + bb.z, acc[ci][rj][3] + bb.w)};
                    *(uint2*)(dst + (size_t)node * 256 + col0) = p;
                }
            }
        }
    }
}

__global__ __launch_bounds__(1024) void scan_kernel(
    const unsigned* __restrict__ count, unsigned* __restrict__ cursor, int N)
{
    __shared__ unsigned part[1024];
    const int t = threadIdx.x;
    const int per = (N + 1023) / 1024;
    const int b = t * per;
    unsigned s = 0;
    for (int i = 0; i < per; i++) if (b + i < N) s += count[b + i];
    part[t] = s;
    __syncthreads();
    for (int off = 1; off < 1024; off <<= 1) {
        unsigned v = (t >= off) ? part[t - off] : 0u;
        __syncthreads();
        part[t] += v;
        __syncthreads();
    }
    unsigned run = (t > 0) ? part[t - 1] : 0u;
    for (int i = 0; i < per; i++) {
        if (b + i < N) {
            unsigned c = count[b + i];
            cursor[b + i] = run;
            run += c;
        }
    }
}

__global__ void scatter_kernel(const int* __restrict__ eidx, int E, int M,
                               unsigned* __restrict__ cursor, int* __restrict__ spair)
{
    const int i = blockIdx.x * 256 + threadIdx.x;
    if (i < M) {
        int s, tg;
        if (i < E) { s = eidx[i]; tg = eidx[E + i]; }
        else       { s = tg = i - E; }
        const unsigned pos = atomicAdd(&cursor[tg], 1u);
        int2* p = (int2*)spair;
        p[pos] = make_int2(s, tg);
    }
}

// Fused: u1 = relu(P'[tgt]+Q[src]) -> GEMM2 -> epi2(raw bf16 keys) -> segmax
__global__ __launch_bounds__(512) void msg_kernel(
    const unsigned short* __restrict__ Pb,
    const unsigned short* __restrict__ Qb,
    const int* __restrict__ spair,   // [M] (src,tgt) pairs, sorted by tgt
    int M,
    const unsigned short* __restrict__ W2b,
    const float* __restrict__ consts,
    const unsigned* __restrict__ mask2,
    unsigned* __restrict__ agg)
{
    __shared__ unsigned short At[64 * 256];   // 32 KiB
    __shared__ int tgt_l[64];

    const int t = threadIdx.x;
    const int base = blockIdx.x * 64;

    // ---- gather+L1: u1 = relu(P'[tgt] + Q[src]) straight into LDS ----
    {
        const int row = t >> 3, part = t & 7;
        const int slot = base + row;
        const int c0 = part * 32;
        if (slot < M) {
            const int2 pr = *(const int2*)(spair + 2 * slot);   // (src, tgt)
            if (part == 0) tgt_l[row] = pr.y;
            const unsigned short* Pp = Pb + (size_t)pr.y * 256 + c0;
            const unsigned short* Qp = Qb + (size_t)pr.x * 256 + c0;
            uint4 P4[4], Q4[4];
            #pragma unroll
            for (int w = 0; w < 4; w++) P4[w] = *(const uint4*)(Pp + w * 8);
            #pragma unroll
            for (int w = 0; w < 4; w++) Q4[w] = *(const uint4*)(Qp + w * 8);
            #pragma unroll
            for (int w = 0; w < 4; w++) {
                uint4 u;
                u.x = ar2(P4[w].x, Q4[w].x);
                u.y = ar2(P4[w].y, Q4[w].y);
                u.z = ar2(P4[w].z, Q4[w].z);
                u.w = ar2(P4[w].w, Q4[w].w);
                *(uint4*)&At[swz(row, c0 + w * 8)] = u;
            }
        } else {
            if (part == 0) tgt_l[row] = -1;
            const uint4 z = {0u, 0u, 0u, 0u};
            #pragma unroll
            for (int w = 0; w < 4; w++) *(uint4*)&At[swz(row, c0 + w * 8)] = z;
        }
    }
    __syncthreads();

    const int lane = t & 63;
    const int wv   = t >> 6;          // 0..7
    const int n16  = lane & 15;
    const int qd   = lane >> 4;
    const int wc   = wv * 32;         // this wave's 32 output cols

    const f32x4 vzero = {0.f, 0.f, 0.f, 0.f};
    f32x4 acc[2][4];
    #pragma unroll
    for (int i = 0; i < 2; i++)
        #pragma unroll
        for (int j = 0; j < 4; j++) acc[i][j] = vzero;

    // ---- GEMM2: A=W2'(BN1-scaled), B=u1 ----
    #pragma unroll
    for (int ks = 0; ks < 8; ks++) {
        const int k0 = ks * 32 + qd * 8;
        bf16x8 a[2], b[4];
        #pragma unroll
        for (int ci = 0; ci < 2; ci++)
            a[ci] = *(const bf16x8*)&W2b[(size_t)(wc + ci * 16 + n16) * 256 + k0];
        #pragma unroll
        for (int rj = 0; rj < 4; rj++)
            b[rj] = *(const bf16x8*)&At[swz(rj * 16 + n16, k0)];
        #pragma unroll
        for (int ci = 0; ci < 2; ci++)
            #pragma unroll
            for (int rj = 0; rj < 4; rj++)
                acc[ci][rj] = __builtin_amdgcn_mfma_f32_16x16x32_bf16(a[ci], b[rj], acc[ci][rj], 0, 0, 0);
    }
    __syncthreads();

    // ---- epi2: r = relu(z2 + b2'') -> raw bf16 bits ^ signmask (BN2 folded
    //      into W3'/b3'; nonneg bf16 bits are monotone as u16 keys) ----
    {
        const float* B2 = consts + 768;
        #pragma unroll
        for (int ci = 0; ci < 2; ci++) {
            const int col0 = wc + ci * 16 + qd * 4;
            const float4 bb = *(const float4*)&B2[col0];
            const uint2 mk = *(const uint2*)&mask2[col0 >> 1];
            #pragma unroll
            for (int rj = 0; rj < 4; rj++) {
                const int row = rj * 16 + n16;
                float r0 = fmaxf(acc[ci][rj][0] + bb.x, 0.f);
                float r1 = fmaxf(acc[ci][rj][1] + bb.y, 0.f);
                float r2 = fmaxf(acc[ci][rj][2] + bb.z, 0.f);
                float r3 = fmaxf(acc[ci][rj][3] + bb.w, 0.f);
                uint2 p = {pkb(r0, r1) ^ mk.x, pkb(r2, r3) ^ mk.y};
                *(uint2*)&At[swz(row, col0)] = p;
            }
        }
    }
    __syncthreads();

    // ---- segmented max: wave = 16 rows x 128 cols, lane = 2 cols ----
    {
        const int r0 = (wv & 3) * 16;
        const int cb = (wv >> 2) * 128 + lane * 2;
        const int myt = (lane < 16) ? tgt_l[r0 + lane] : -1;
        int curT = -1;
        unsigned m0 = 0, m1 = 0;
        for (int r = 0; r < 16; r++) {
            const int tg = __shfl(myt, r);            // wave-uniform
            const unsigned k2 = *(const unsigned*)&At[swz(r0 + r, cb)];
            const unsigned k0 = k2 & 0xFFFFu, k1 = k2 >> 16;
            if (tg != curT) {
                if (curT >= 0) {
                    unsigned* p = &agg[(size_t)curT * 256 + cb];
                    atomicMax(p, m0); atomicMax(p + 1, m1);
                }
                curT = tg; m0 = k0; m1 = k1;
            } else {
                m0 = m0 > k0 ? m0 : k0;
                m1 = m1 > k1 ? m1 : k1;
            }
        }
        if (curT >= 0) {
            unsigned* p = &agg[(size_t)curT * 256 + cb];
            atomicMax(p, m0); atomicMax(p + 1, m1);
        }
    }
}

// Final layer: agg keys -> XOR unmask (raw bf16 r) -> GEMM3(W3'=W3*s2) ->
// bias(b3')+ReLU+BN3 -> fp32 out
__global__ __launch_bounds__(256) void out_kernel(
    const unsigned* __restrict__ agg, int N,
    const unsigned short* __restrict__ W3b,
    const float* __restrict__ consts,
    const unsigned* __restrict__ mask2,
    float* __restrict__ out)
{
    __shared__ unsigned short At[32 * 256];

    const int t = threadIdx.x;
    const int base = blockIdx.x * 32;

    {
        const int row = t >> 3, part = t & 7;
        const int node = base + row;
        const int c0 = part * 32;
        if (node < N) {
            const unsigned* ap = agg + (size_t)node * 256 + c0;
            #pragma unroll
            for (int w = 0; w < 4; w++) {
                uint4 a = *(const uint4*)(ap + w * 8);
                uint4 b = *(const uint4*)(ap + w * 8 + 4);
                const uint4 mk = *(const uint4*)&mask2[(c0 + w * 8) >> 1];
                uint4 p;
                p.x = (a.x | (a.y << 16)) ^ mk.x;
                p.y = (a.z | (a.w << 16)) ^ mk.y;
                p.z = (b.x | (b.y << 16)) ^ mk.z;
                p.w = (b.z | (b.w << 16)) ^ mk.w;
                *(uint4*)&At[swz(row, c0 + w * 8)] = p;
            }
        } else {
            const uint4 z = {0u, 0u, 0u, 0u};
            #pragma unroll
            for (int w = 0; w < 4; w++) *(uint4*)&At[swz(row, c0 + w * 8)] = z;
        }
    }
    __syncthreads();

    const int lane = t & 63;
    const int wv   = t >> 6;
    const int n16  = lane & 15;
    const int qd   = lane >> 4;
    const int wc   = wv * 64;

    const f32x4 vzero = {0.f, 0.f, 0.f, 0.f};
    f32x4 acc[2][4];
    #pragma unroll
    for (int i = 0; i < 2; i++)
        #pragma unroll
        for (int j = 0; j < 4; j++) acc[i][j] = vzero;

    #pragma unroll
    for (int ks = 0; ks < 8; ks++) {
        const int k0 = ks * 32 + qd * 8;
        bf16x8 a[2];
        #pragma unroll
        for (int ri = 0; ri < 2; ri++)
            a[ri] = *(const bf16x8*)&At[swz(ri * 16 + n16, k0)];
        #pragma unroll
        for (int ci = 0; ci < 4; ci++) {
            bf16x8 b = *(const bf16x8*)&W3b[(size_t)(wc + ci * 16 + n16) * 256 + k0];
            #pragma unroll
            for (int ri = 0; ri < 2; ri++)
                acc[ri][ci] = __builtin_amdgcn_mfma_f32_16x16x32_bf16(a[ri], b, acc[ri][ci], 0, 0, 0);
        }
    }

    {
        const float* B3 = consts + 1536;
        const float* S3 = consts + 1536 + 256;
        const float* T3 = consts + 1536 + 512;
        #pragma unroll
        for (int ci = 0; ci < 4; ci++) {
            const int col = wc + ci * 16 + n16;
            const float bb = B3[col], ss = S3[col], tt = T3[col];
            #pragma unroll
            for (int ri = 0; ri < 2; ri++) {
                #pragma unroll
                for (int r = 0; r < 4; r++) {
                    const int row = ri * 16 + qd * 4 + r;
                    const int node = base + row;
                    if (node < N) {
                        float v = fmaxf(acc[ri][ci][r] + bb, 0.f) * ss + tt;
                        out[(size_t)node * 256 + col] = v;
                    }
                }
            }
        }
    }
}

extern "C" void kernel_launch(void* const* d_in, const int* in_sizes, int n_in,
                              void* d_out, int out_size, void* d_ws, size_t ws_size,
                              hipStream_t stream)
{
    const float* x  = (const float*)d_in[0];
    const int* eidx = (const int*)d_in[1];
    const int N = in_sizes[0] / 128;
    const int NX = in_sizes[0];
    const int E = in_sizes[1] / 2;
    const int M = E + N;

    char* ws = (char*)d_ws;
    unsigned short* W1b = (unsigned short*)(ws);
    unsigned short* W2b = (unsigned short*)(ws + 131072);
    unsigned short* W3b = (unsigned short*)(ws + 262144);
    float* consts       = (float*)(ws + 393216);                 // 2304 f32
    unsigned* mask2     = (unsigned*)(ws + 402432);              // 128 u32
    size_t off = 402944;
    unsigned short* xb  = (unsigned short*)(ws + off); off += (size_t)NX * 2;
    unsigned* agg       = (unsigned*)(ws + off);       off += (size_t)N * 256 * 4;
    unsigned* count     = (unsigned*)(ws + off);       off += (size_t)N * 4;
    unsigned* cursor    = (unsigned*)(ws + off);       off += (size_t)N * 4;
    int* spair          = (int*)(ws + off);            off += (size_t)M * 8;
    unsigned short* Pb  = (unsigned short*)(ws + off); off += (size_t)N * 256 * 2;
    unsigned short* Qb  = (unsigned short*)(ws + off);

    hipMemsetAsync(agg, 0, (size_t)N * 256 * 4, stream);
    hipMemsetAsync(count, 0, (size_t)N * 4, stream);

    int work = NX;
    if (M > work) work = M;
    if (65536 > work) work = 65536;
    hipLaunchKernelGGL(prep_kernel, dim3((work + 255) / 256), dim3(256), 0, stream,
        x, eidx, E, M, NX,
        (const float*)d_in[2], (const float*)d_in[8], (const float*)d_in[14],
        (const float*)d_in[3], (const float*)d_in[4], (const float*)d_in[5],
        (const float*)d_in[6], (const float*)d_in[7],
        (const float*)d_in[9], (const float*)d_in[10], (const float*)d_in[11],
        (const float*)d_in[12], (const float*)d_in[13],
        (const float*)d_in[15], (const float*)d_in[16], (const float*)d_in[17],
        (const float*)d_in[18], (const float*)d_in[19],
        W1b, W2b, W3b, consts, mask2, xb, count);

    hipLaunchKernelGGL(pq_kernel, dim3((N + 63) / 64), dim3(512), 0, stream,
        xb, N, W1b, consts, Pb, Qb);

    hipLaunchKernelGGL(scan_kernel, dim3(1), dim3(1024), 0, stream,
        count, cursor, N);
    hipLaunchKernelGGL(scatter_kernel, dim3((M + 255) / 256), dim3(256), 0, stream,
        eidx, E, M, cursor, spair);

    hipLaunchKernelGGL(msg_kernel, dim3((M + 63) / 64), dim3(512), 0, stream,
        Pb, Qb, spair, M, W2b, consts, mask2, agg);

    hipLaunchKernelGGL(out_kernel, dim3((N + 31) / 32), dim3(256), 0, stream,
        agg, N, W3b, consts, mask2, (float*)d_out);
}